// Round 10
// baseline (384.048 us; speedup 1.0000x reference)
//
#include <hip/hip_runtime.h>
#include <cstdint>
#include <cstddef>

// Problem constants (match reference)
#define NS 4000
#define NG 50000
#define NE 250000
#define DIM 128
#define NDST_TOT (NG + NS)          // 54000 combined CSR rows (sg then gs)

typedef __bf16 bf16_t;
typedef bf16_t bf16x8 __attribute__((ext_vector_type(8)));
typedef bf16_t bf16x4 __attribute__((ext_vector_type(4)));
typedef float floatx4 __attribute__((ext_vector_type(4)));

template <int V> struct BV {};
template <> struct BV<2> { typedef bf16_t T __attribute__((ext_vector_type(2))); };
template <> struct BV<4> { typedef bf16_t T __attribute__((ext_vector_type(4))); };

// ---------------------------------------------------------------------------
// hist: per-dst degree counts for both relations (combined index space)
// ---------------------------------------------------------------------------
__global__ void hist2(const int* __restrict__ sgd, const int* __restrict__ gsd,
                      int* __restrict__ cnt) {
  int e = blockIdx.x * 256 + threadIdx.x;
  if (e >= NE) return;
  atomicAdd(cnt + sgd[e], 1);
  atomicAdd(cnt + NG + gsd[e], 1);
}

// ---------------------------------------------------------------------------
// 2-kernel parallel scan over n=54000 (53 blocks of 1024).
// NOTE: do NOT replace with a single-block serial-segment scan — measured
// 103 us (R8): per-thread serial global reads on one CU eat ~900-cyc
// cross-XCD misses. Parallel+coalesced is ~10 us total.
// scan1: per-chunk exclusive scan + chunk totals; scan3: each block
// wave-reduces its csum prefix (blockIdx < 64) and adds it.
// ---------------------------------------------------------------------------
__global__ __launch_bounds__(1024) void scan1(const int* __restrict__ cnt,
                                              int* __restrict__ rp,
                                              int* __restrict__ csum, int n) {
  __shared__ int wsum[16];
  int i = blockIdx.x * 1024 + threadIdx.x;
  int lane = threadIdx.x & 63, w = threadIdx.x >> 6;
  int v = (i < n) ? cnt[i] : 0;
  int x = v;
#pragma unroll
  for (int off = 1; off < 64; off <<= 1) {
    int y = __shfl_up(x, off);
    if (lane >= off) x += y;
  }
  if (lane == 63) wsum[w] = x;
  __syncthreads();
  if (w == 0 && lane < 16) {
    int s = wsum[lane];
#pragma unroll
    for (int off = 1; off < 16; off <<= 1) {
      int y = __shfl_up(s, off);
      if (lane >= off) s += y;
    }
    wsum[lane] = s;
  }
  __syncthreads();
  int incl = x + (w ? wsum[w - 1] : 0);
  if (i < n) rp[i] = incl - v;
  if (threadIdx.x == 1023) csum[blockIdx.x] = incl;
}

__global__ __launch_bounds__(1024) void scan3(int* __restrict__ rp,
                                              const int* __restrict__ csum, int n) {
  __shared__ int pfx_s;
  if (threadIdx.x < 64) {
    int lane = threadIdx.x;
    int v = (lane < (int)blockIdx.x) ? csum[lane] : 0;   // blockIdx.x <= 52
#pragma unroll
    for (int off = 32; off > 0; off >>= 1) v += __shfl_down(v, off);
    if (lane == 0) pfx_s = v;
  }
  __syncthreads();
  int i = blockIdx.x * 1024 + threadIdx.x;
  if (i < n) rp[i] += pfx_s;
  if (i == 0) rp[n] = 2 * NE;                // static total sentinel
}

// ---------------------------------------------------------------------------
// Fused scatter + prep. Blocks [0, SCAT_B): CSR scatter of packed (src,ea)
// payloads. Blocks [SCAT_B, ...): 8 weight transposes (Wt[n][k]=bf16(W[k][n]))
// + bf16 casts of x_mrna / x_gene.
// ---------------------------------------------------------------------------
#define SCAT_B 1954                 // ceil(2*NE/256)
#define WT_TOT 143360               // 4*16384 + 2*32768 + 4096 + 8192
struct SPArgs {
  // scatter
  const int* sgd; const int* gsd; const int* sgs; const int* gss;
  const float* easg; const float* eags;
  const int* rp; int* cur; uint2* meta;
  // prep
  const float* W[8]; bf16_t* Wt[8]; int N[8]; int e0[8];
  const float* xm; bf16_t* xbm;
  const float* xg; bf16_t* xbg;
};

__global__ __launch_bounds__(256) void scatter_prep(SPArgs a) {
  if (blockIdx.x < SCAT_B) {
    int t = blockIdx.x * 256 + threadIdx.x;
    if (t < NE) {
      int d = a.sgd[t];
      int pos = atomicAdd(a.cur + d, 1);
      uint2 pv; pv.x = (unsigned)a.sgs[t]; pv.y = __float_as_uint(a.easg[t]);
      a.meta[a.rp[d] + pos] = pv;
    } else if (t < 2 * NE) {
      int e = t - NE;
      int d = a.gsd[e];
      int pos = atomicAdd(a.cur + NG + d, 1);
      uint2 pv; pv.x = (unsigned)a.gss[e]; pv.y = __float_as_uint(a.eags[e]);
      a.meta[a.rp[NG + d] + pos] = pv;
    }
  } else {
    int u = (blockIdx.x - SCAT_B) * 256 + threadIdx.x;
    if (u < WT_TOT) {
      int c = 0;
#pragma unroll
      for (int i = 1; i < 8; i++) if (u >= a.e0[i]) c = i;
      int idx = u - a.e0[c];
      int N = a.N[c];
      int k = idx / N, n = idx - k * N;
      a.Wt[c][n * 128 + k] = (bf16_t)a.W[c][idx];
    } else if (u < WT_TOT + 128000) {
      int j = (u - WT_TOT) * 4;
      float4 v = *reinterpret_cast<const float4*>(a.xm + j);
      bf16x4 b;
      b[0] = (bf16_t)v.x; b[1] = (bf16_t)v.y; b[2] = (bf16_t)v.z; b[3] = (bf16_t)v.w;
      *reinterpret_cast<bf16x4*>(a.xbm + j) = b;
    } else {
      int j = (u - WT_TOT - 128000) * 4;
      float4 v = *reinterpret_cast<const float4*>(a.xg + j);
      bf16x4 b;
      b[0] = (bf16_t)v.x; b[1] = (bf16_t)v.y; b[2] = (bf16_t)v.z; b[3] = (bf16_t)v.w;
      *reinterpret_cast<bf16x4*>(a.xbg + j) = b;
    }
  }
}

// ---------------------------------------------------------------------------
// Multi-config MFMA GEMM, runtime column count: Y = bf16(X @ W + b).
// X bf16 [M,128]; Wt bf16 [N][128]; N in {32,64,128,256}.
// C/D: col = lane&15, row = quad*4 + reg   (verified gfx950 mapping)
// ---------------------------------------------------------------------------
template <int NCFG>
struct GArgs {
  const bf16_t* X[NCFG];
  const bf16_t* Wt[NCFG];
  const float* Bv[NCFG];
  bf16_t* Y[NCFG];
  int M[NCFG];
  int Ncol[NCFG];
  int blk0[NCFG];
};

template <int NCFG>
__global__ __launch_bounds__(256) void gemm_multi(GArgs<NCFG> a) {
  int c = 0;
#pragma unroll
  for (int i = 1; i < NCFG; i++) if ((int)blockIdx.x >= a.blk0[i]) c = i;
  const bf16_t* X = a.X[c];
  const bf16_t* Wt = a.Wt[c];
  const float* B = a.Bv[c];
  bf16_t* Y = a.Y[c];
  int M = a.M[c];
  int N = a.Ncol[c];

  int wv = threadIdx.x >> 6, lane = threadIdx.x & 63;
  int m16 = lane & 15, quad = lane >> 4;
  int row0 = (blockIdx.x - a.blk0[c]) * 64 + wv * 16;
  int arow = row0 + m16;
  const bf16_t* xp = X + (size_t)arow * DIM + quad * 8;

  bf16x8 afrag[4];
#pragma unroll
  for (int kk = 0; kk < 4; kk++) {
    bf16x8 av = {};
    if (arow < M) av = *reinterpret_cast<const bf16x8*>(xp + kk * 32);
    afrag[kk] = av;
  }

  int ncols = N >> 4;
#pragma unroll 2
  for (int nt = 0; nt < ncols; nt++) {
    int col = nt * 16 + m16;
    const bf16_t* bptr = Wt + (size_t)col * DIM + quad * 8;
    floatx4 acc = {0.f, 0.f, 0.f, 0.f};
#pragma unroll
    for (int kk = 0; kk < 4; kk++) {
      bf16x8 b = *reinterpret_cast<const bf16x8*>(bptr + kk * 32);
      acc = __builtin_amdgcn_mfma_f32_16x16x32_bf16(afrag[kk], b, acc, 0, 0, 0);
    }
    float bias = B[col];
    int orow = row0 + quad * 4;
#pragma unroll
    for (int r = 0; r < 4; r++)
      if (orow + r < M) Y[(size_t)(orow + r) * N + col] = (bf16_t)(acc[r] + bias);
  }
}

// ---------------------------------------------------------------------------
// Fused phase-C gather.
// Blocks [0, SGB): sg relation, 4 waves/block, each wave FOUR dsts.
//   Destination index per edge is WAVE-UNIFORM (sorted CSR + uniform edge
//   position) -> readfirstlane + scalar branch, full edge math with constant
//   accumulator indices (saves ~40% VALU vs flag-weighted accumulate; R9's
//   gatC was VALUBusy=80%).
// Blocks [SGB, SGB+NS): gs relation, one block per dst, 4 subwaves, LDS comb.
// Both: C=32, VEC=2, bf16 in/out, fused bias(/sl)/relu epilogue.
// ---------------------------------------------------------------------------
#define SGB 3125                    // 50000 dsts / (4 waves * 4 dsts)
__global__ __launch_bounds__(256) void gatC(
    const int* __restrict__ rp, const uint2* __restrict__ meta,
    const float* __restrict__ WeS, const float* __restrict__ attS,
    const float* __restrict__ boS,
    const bf16_t* __restrict__ xlS, const bf16_t* __restrict__ xrS,
    bf16_t* __restrict__ outS,
    const float* __restrict__ WeG, const float* __restrict__ attG,
    const float* __restrict__ boG,
    const bf16_t* __restrict__ xlG, const bf16_t* __restrict__ xrG,
    const bf16_t* __restrict__ slG, bf16_t* __restrict__ outG) {
  typedef BV<2>::T bvec;
  __shared__ float lacc[4][128];
  __shared__ float lden[4][64];
  int wv = threadIdx.x >> 6, lane = threadIdx.x & 63;

  if (blockIdx.x < SGB) {
    // ---------------- sg: 4 dsts per wave ----------------
    int wid = blockIdx.x * 4 + wv;
    int d0 = wid * 4;
    int q = lane < 5 ? lane : 0;
    int rv = rp[d0 + q];
    int b0 = __shfl(rv, 0), m1 = __shfl(rv, 1), m2 = __shfl(rv, 2);
    int m3 = __shfl(rv, 3), e1 = __shfl(rv, 4);

    float2 wev = *reinterpret_cast<const float2*>(WeS + lane * 2);
    float2 atv = *reinterpret_cast<const float2*>(attS + lane * 2);
    float xrA[4][2];
#pragma unroll
    for (int r = 0; r < 4; r++) {
      bvec xb = *reinterpret_cast<const bvec*>(xrS + (size_t)(d0 + r) * 128 + lane * 2);
      xrA[r][0] = (float)xb[0]; xrA[r][1] = (float)xb[1];
    }
    float ac[4][2] = {};
    float dn[4] = {};

    for (int i0 = b0; i0 < e1; i0 += 64) {
      int cnt = min(64, e1 - i0);
      int s_l = 0; float ea_l = 0.f;
      if (lane < cnt) {
        uint2 mv = meta[i0 + lane];
        s_l = (int)mv.x; ea_l = __uint_as_float(mv.y);
      }
      for (int k0 = 0; k0 < cnt; k0 += 8) {
        int s8[8], gi[8]; float ea8[8];
        bvec raw[8];
#pragma unroll
        for (int g = 0; g < 8; g++) {
          int kk = (k0 + g < cnt) ? k0 + g : k0;
          s8[g] = __shfl(s_l, kk);
          ea8[g] = __shfl(ea_l, kk);
          gi[g] = i0 + kk;
        }
#pragma unroll
        for (int g = 0; g < 8; g++)
          raw[g] = *reinterpret_cast<const bvec*>(xlS + (size_t)s8[g] * 128 + lane * 2);

#define SG_EDGE_BODY(r)                                                  \
        {                                                                \
          float m0 = xf0 + xrA[r][0] + ea8[g] * wev.x;                   \
          float m1v = xf1 + xrA[r][1] + ea8[g] * wev.y;                  \
          m0 = m0 > 0.f ? m0 : 0.2f * m0;       /* leaky_relu(.,0.2) */  \
          m1v = m1v > 0.f ? m1v : 0.2f * m1v;                            \
          float p = fmaf(m0, atv.x, m1v * atv.y);                        \
          p += __shfl_xor(p, 1);                                         \
          p += __shfl_xor(p, 2);                                         \
          p += __shfl_xor(p, 4);                                         \
          p += __shfl_xor(p, 8);                /* head-wide logit */    \
          float ex = __expf(p);                                          \
          if (k0 + g >= cnt) ex = 0.f;          /* mask tail repeats */  \
          dn[r] += ex;                                                   \
          ac[r][0] = fmaf(ex, xf0, ac[r][0]);                            \
          ac[r][1] = fmaf(ex, xf1, ac[r][1]);                            \
        }

#pragma unroll
        for (int g = 0; g < 8; g++) {
          float xf0 = (float)raw[g][0], xf1 = (float)raw[g][1];
          // wave-uniform destination select -> scalar branch
          int idxu = __builtin_amdgcn_readfirstlane(
              (int)(gi[g] >= m1) + (int)(gi[g] >= m2) + (int)(gi[g] >= m3));
          if (idxu == 0) SG_EDGE_BODY(0)
          else if (idxu == 1) SG_EDGE_BODY(1)
          else if (idxu == 2) SG_EDGE_BODY(2)
          else SG_EDGE_BODY(3)
        }
#undef SG_EDGE_BODY
      }
    }
    int j = lane * 2;
    float bo0 = boS[j], bo1 = boS[j + 1];
#pragma unroll
    for (int r = 0; r < 4; r++) {
      float iv = dn[r] > 0.f ? 1.f / dn[r] : 0.f;
      bvec o;
      o[0] = (bf16_t)fmaxf(ac[r][0] * iv + bo0, 0.f);
      o[1] = (bf16_t)fmaxf(ac[r][1] * iv + bo1, 0.f);
      *reinterpret_cast<bvec*>(outS + (size_t)(d0 + r) * 128 + j) = o;
    }
  } else {
    // ---------------- gs: one block per dst ----------------
    int d = blockIdx.x - SGB;
    const int* rpg = rp + NG;
    float2 wev = *reinterpret_cast<const float2*>(WeG + lane * 2);
    float2 atv = *reinterpret_cast<const float2*>(attG + lane * 2);
    bvec xrb = *reinterpret_cast<const bvec*>(xrG + (size_t)d * 128 + lane * 2);
    float xrv[2] = {(float)xrb[0], (float)xrb[1]};
    float acc[2] = {0.f, 0.f};
    float den = 0.f;

    int beg = rpg[d], end = rpg[d + 1];
    for (int i0 = beg + wv * 16; i0 < end; i0 += 64) {
      int cnt = min(16, end - i0);
      int s_l = 0; float ea_l = 0.f;
      if (lane < cnt) {
        uint2 mv = meta[i0 + lane];
        s_l = (int)mv.x; ea_l = __uint_as_float(mv.y);
      }
      for (int k0 = 0; k0 < cnt; k0 += 8) {
        int s8[8]; float ea8[8];
        bvec raw[8];
#pragma unroll
        for (int g = 0; g < 8; g++) {
          int kk = (k0 + g < cnt) ? k0 + g : k0;
          s8[g] = __shfl(s_l, kk);
          ea8[g] = __shfl(ea_l, kk);
        }
#pragma unroll
        for (int g = 0; g < 8; g++)
          raw[g] = *reinterpret_cast<const bvec*>(xlG + (size_t)s8[g] * 128 + lane * 2);
#pragma unroll
        for (int g = 0; g < 8; g++) {
          float xf0 = (float)raw[g][0], xf1 = (float)raw[g][1];
          float m0 = xf0 + xrv[0] + ea8[g] * wev.x;
          float m1v = xf1 + xrv[1] + ea8[g] * wev.y;
          m0 = m0 > 0.f ? m0 : 0.2f * m0;
          m1v = m1v > 0.f ? m1v : 0.2f * m1v;
          float p = fmaf(m0, atv.x, m1v * atv.y);
          p += __shfl_xor(p, 1);
          p += __shfl_xor(p, 2);
          p += __shfl_xor(p, 4);
          p += __shfl_xor(p, 8);
          float ex = __expf(p);
          if (k0 + g >= cnt) ex = 0.f;
          den += ex;
          acc[0] = fmaf(ex, xf0, acc[0]);
          acc[1] = fmaf(ex, xf1, acc[1]);
        }
      }
    }
    lacc[wv][lane * 2] = acc[0];
    lacc[wv][lane * 2 + 1] = acc[1];
    lden[wv][lane] = den;
    __syncthreads();
    if (wv != 0) return;
#pragma unroll
    for (int s = 1; s < 4; s++) {
      acc[0] += lacc[s][lane * 2];
      acc[1] += lacc[s][lane * 2 + 1];
      den += lden[s][lane];
    }
    float inv = den > 0.f ? 1.f / den : 0.f;
    int j = lane * 2;
    bvec o;
#pragma unroll
    for (int v = 0; v < 2; v++) {
      int jj = j + v;
      float val = acc[v] * inv + boG[jj] + (float)slG[(size_t)d * 32 + (jj & 31)];
      o[v] = (bf16_t)(val > 0.f ? val : 0.f);
    }
    *reinterpret_cast<bvec*>(outG + (size_t)d * 128 + j) = o;
  }
}

// ---------------------------------------------------------------------------
// Phase-E gather: one block per dst (4 subwaves, LDS combine), C=64, VEC=4.
// out fp32 = relu(mean_h(acc_h/den_h) + bo + sl)
// ---------------------------------------------------------------------------
__global__ __launch_bounds__(256) void gatE(
    const int* __restrict__ rp, const uint2* __restrict__ meta,
    const float* __restrict__ We, const float* __restrict__ att,
    const bf16_t* __restrict__ xl, const bf16_t* __restrict__ xr,
    const float* __restrict__ bo, const bf16_t* __restrict__ sl,
    float* __restrict__ out) {
  typedef BV<4>::T bvec;
  __shared__ float lacc[4][256];
  __shared__ float lden[4][64];
  int wv = threadIdx.x >> 6, lane = threadIdx.x & 63;
  int d = blockIdx.x;

  float wev[4], atv[4], xrv[4], acc[4];
  *reinterpret_cast<float4*>(wev) = *reinterpret_cast<const float4*>(We + lane * 4);
  *reinterpret_cast<float4*>(atv) = *reinterpret_cast<const float4*>(att + lane * 4);
  bvec xrb = *reinterpret_cast<const bvec*>(xr + (size_t)d * 256 + lane * 4);
#pragma unroll
  for (int v = 0; v < 4; v++) { xrv[v] = (float)xrb[v]; acc[v] = 0.f; }
  float den = 0.f;

  int beg = rp[d], end = rp[d + 1];
  for (int i0 = beg + wv * 16; i0 < end; i0 += 64) {
    int cnt = min(16, end - i0);
    int s_l = 0; float ea_l = 0.f;
    if (lane < cnt) {
      uint2 mv = meta[i0 + lane];
      s_l = (int)mv.x; ea_l = __uint_as_float(mv.y);
    }
    for (int k0 = 0; k0 < cnt; k0 += 8) {
      int s8[8]; float ea8[8];
      bvec raw[8];
#pragma unroll
      for (int g = 0; g < 8; g++) {
        int kk = (k0 + g < cnt) ? k0 + g : k0;
        s8[g] = __shfl(s_l, kk);
        ea8[g] = __shfl(ea_l, kk);
      }
#pragma unroll
      for (int g = 0; g < 8; g++)
        raw[g] = *reinterpret_cast<const bvec*>(xl + (size_t)s8[g] * 256 + lane * 4);
#pragma unroll
      for (int g = 0; g < 8; g++) {
        float xf[4];
        float p = 0.f;
#pragma unroll
        for (int v = 0; v < 4; v++) {
          xf[v] = (float)raw[g][v];
          float mm = xf[v] + xrv[v] + ea8[g] * wev[v];
          mm = mm > 0.f ? mm : 0.2f * mm;
          p = fmaf(mm, atv[v], p);
        }
        p += __shfl_xor(p, 1);
        p += __shfl_xor(p, 2);
        p += __shfl_xor(p, 4);
        p += __shfl_xor(p, 8);
        float ex = __expf(p);
        if (k0 + g >= cnt) ex = 0.f;
        den += ex;
#pragma unroll
        for (int v = 0; v < 4; v++) acc[v] = fmaf(ex, xf[v], acc[v]);
      }
    }
  }

#pragma unroll
  for (int v = 0; v < 4; v++) lacc[wv][lane * 4 + v] = acc[v];
  lden[wv][lane] = den;
  __syncthreads();
  if (wv != 0) return;
#pragma unroll
  for (int s = 1; s < 4; s++) {
#pragma unroll
    for (int v = 0; v < 4; v++) acc[v] += lacc[s][lane * 4 + v];
    den += lden[s][lane];
  }
  float inv = den > 0.f ? 1.f / den : 0.f;
#pragma unroll
  for (int v = 0; v < 4; v++) {
    float s_ = acc[v] * inv;
    s_ += __shfl_xor(s_, 16);
    s_ += __shfl_xor(s_, 32);                  // sum over the 4 heads
    if (lane < 16) {
      int c = (lane & 15) * 4 + v;
      float val = 0.25f * s_ + bo[c] + (float)sl[(size_t)d * 64 + c];
      out[(size_t)d * 64 + c] = val > 0.f ? val : 0.f;
    }
  }
}

// ---------------------------------------------------------------------------

static inline int nblk(long long threads) { return (int)((threads + 255) / 256); }
static inline int nrow(int M, int R) { return (M + R - 1) / R; }

extern "C" void kernel_launch(void* const* d_in, const int* in_sizes, int n_in,
                              void* d_out, int out_size, void* d_ws, size_t ws_size,
                              hipStream_t stream) {
  const float* x_mrna = (const float*)d_in[0];
  const float* x_gene = (const float*)d_in[1];
  const int* sg_src = (const int*)d_in[2];
  const int* sg_dst = (const int*)d_in[3];
  const int* gs_src = (const int*)d_in[4];
  const int* gs_dst = (const int*)d_in[5];
  const float* ea_sg = (const float*)d_in[6];
  const float* ea_gs = (const float*)d_in[7];
  const float* Wl1_sg = (const float*)d_in[8];
  const float* bl1_sg = (const float*)d_in[9];
  const float* Wr1_sg = (const float*)d_in[10];
  const float* br1_sg = (const float*)d_in[11];
  const float* We1_sg = (const float*)d_in[12];
  const float* att1_sg = (const float*)d_in[13];
  const float* bo1_sg = (const float*)d_in[14];
  const float* Wl1_gs = (const float*)d_in[15];
  const float* bl1_gs = (const float*)d_in[16];
  const float* Wr1_gs = (const float*)d_in[17];
  const float* br1_gs = (const float*)d_in[18];
  const float* We1_gs = (const float*)d_in[19];
  const float* att1_gs = (const float*)d_in[20];
  const float* bo1_gs = (const float*)d_in[21];
  const float* Wl3_gs = (const float*)d_in[22];
  const float* bl3_gs = (const float*)d_in[23];
  const float* Wr3_gs = (const float*)d_in[24];
  const float* br3_gs = (const float*)d_in[25];
  const float* We3_gs = (const float*)d_in[26];
  const float* att3_gs = (const float*)d_in[27];
  const float* bo3_gs = (const float*)d_in[28];
  const float* Wsl1 = (const float*)d_in[29];
  const float* bsl1 = (const float*)d_in[30];
  const float* Wsl3 = (const float*)d_in[31];
  const float* bsl3 = (const float*)d_in[32];

  // ---- workspace arena (fp32 element offsets), bf16 throughout ----
  float* ws = (float*)d_ws;
  bf16_t* xl1_gs = (bf16_t*)(ws + 0);        // bf16[50000*128] dead after C
  bf16_t* xl1_sg = (bf16_t*)(ws + 3200000);  // bf16[4000*128]  dead after C
  bf16_t* xr1_sg = (bf16_t*)(ws + 3456000);  // bf16[50000*128] dead after C
  bf16_t* xr1_gs = (bf16_t*)(ws + 6656000);  // bf16[4000*128]  dead after C
  bf16_t* xl3    = (bf16_t*)(ws + 0);        // bf16[50000*256] aliases [0,6.4M)
  bf16_t* xr3    = (bf16_t*)(ws + 6400000);  // bf16[4000*256]  aliases tail
  bf16_t* xb_mrna = (bf16_t*)(ws + 6912000); // bf16[4000*128]
  bf16_t* xb_gene = (bf16_t*)(ws + 7168000); // bf16[50000*128]
  bf16_t* x1_gene = (bf16_t*)(ws + 10368000);// bf16[50000*128]
  bf16_t* x1_mrna = (bf16_t*)(ws + 13568000);// bf16[4000*128]
  bf16_t* sl1    = (bf16_t*)(ws + 13824000); // bf16[4000*32]
  bf16_t* sl3    = (bf16_t*)(ws + 13856000); // bf16[4000*64]
  int*   ib      = (int*)(ws + 13920000);
  int* cnt  = ib + 0;                   // [54000] } zeroed together
  int* cur  = ib + 54000;               // [54000] }
  int* rpc  = ib + 108000;              // [54001]
  int* csum = ib + 162002;              // [64]
  uint2* meta = (uint2*)(ib + 162066);  // [500000] packed (src, ea), 8B-aligned
  bf16_t* wtb = (bf16_t*)(ib + 1162066);// [143360] bf16 transposed weights
  // end: ib + 1233746 ints -> total ~60.6 MB

  bf16_t* wt_l1sg = wtb + 0;
  bf16_t* wt_r1sg = wtb + 16384;
  bf16_t* wt_l1gs = wtb + 32768;
  bf16_t* wt_r1gs = wtb + 49152;
  bf16_t* wt_l3   = wtb + 65536;   // [256*128]
  bf16_t* wt_r3   = wtb + 98304;   // [256*128]
  bf16_t* wt_sl1  = wtb + 131072;  // [32*128]
  bf16_t* wt_sl3  = wtb + 135168;  // [64*128]

  // zero CSR counters (ws is poisoned 0xAA before every timed call)
  hipMemsetAsync(cnt, 0, 108000 * sizeof(int), stream);

  // ---- phase A: CSR build (parallel 2-kernel scan) ----
  hist2<<<nblk(NE), 256, 0, stream>>>(sg_dst, gs_dst, cnt);
  int nchunks = (NDST_TOT + 1023) / 1024;            // 53
  scan1<<<nchunks, 1024, 0, stream>>>(cnt, rpc, csum, NDST_TOT);
  scan3<<<nchunks, 1024, 0, stream>>>(rpc, csum, NDST_TOT);
  {
    SPArgs sa;
    sa.sgd = sg_dst; sa.gsd = gs_dst; sa.sgs = sg_src; sa.gss = gs_src;
    sa.easg = ea_sg; sa.eags = ea_gs; sa.rp = rpc; sa.cur = cur; sa.meta = meta;
    const float* Wsrc[8] = {Wl1_sg, Wr1_sg, Wl1_gs, Wr1_gs, Wl3_gs, Wr3_gs, Wsl1, Wsl3};
    bf16_t* Wdst[8] = {wt_l1sg, wt_r1sg, wt_l1gs, wt_r1gs, wt_l3, wt_r3, wt_sl1, wt_sl3};
    int Nn[8] = {128, 128, 128, 128, 256, 256, 32, 64};
    int e0[8] = {0, 16384, 32768, 49152, 65536, 98304, 131072, 135168};
    for (int i = 0; i < 8; i++) { sa.W[i] = Wsrc[i]; sa.Wt[i] = Wdst[i]; sa.N[i] = Nn[i]; sa.e0[i] = e0[i]; }
    sa.xm = x_mrna; sa.xbm = xb_mrna;
    sa.xg = x_gene; sa.xbg = xb_gene;
    scatter_prep<<<SCAT_B + 7310, 256, 0, stream>>>(sa);  // 9264 blocks
  }

  // ---- phase B: 5 fused layer-1 GEMMs (incl. sl1) ----
  {
    GArgs<5> ga;
    const bf16_t* Xs[5] = {xb_mrna, xb_gene, xb_gene, xb_mrna, xb_mrna};
    const bf16_t* Ws[5] = {wt_l1sg, wt_r1sg, wt_l1gs, wt_r1gs, wt_sl1};
    const float* Bs[5] = {bl1_sg, br1_sg, bl1_gs, br1_gs, bsl1};
    bf16_t* Ys[5] = {xl1_sg, xr1_sg, xl1_gs, xr1_gs, sl1};
    int Ms[5] = {NS, NG, NG, NS, NS};
    int Ns[5] = {128, 128, 128, 128, 32};
    int b0 = 0;
    for (int i = 0; i < 5; i++) {
      ga.X[i] = Xs[i]; ga.Wt[i] = Ws[i]; ga.Bv[i] = Bs[i]; ga.Y[i] = Ys[i];
      ga.M[i] = Ms[i]; ga.Ncol[i] = Ns[i]; ga.blk0[i] = b0;
      b0 += nrow(Ms[i], 64);
    }
    gemm_multi<5><<<b0, 256, 0, stream>>>(ga);   // 1753 blocks
  }

  // ---- phase C: fused layer-1 gathers (sg 4-dst waves + gs blocks) ----
  gatC<<<SGB + NS, 256, 0, stream>>>(
      rpc, meta,
      We1_sg, att1_sg, bo1_sg, xl1_sg, xr1_sg, x1_gene,
      We1_gs, att1_gs, bo1_gs, xl1_gs, xr1_gs, sl1, x1_mrna);

  // ---- phase D: 3 fused layer-3 GEMMs (incl. sl3) ----
  {
    GArgs<3> ga;
    const bf16_t* Xs[3] = {x1_gene, x1_mrna, x1_mrna};
    const bf16_t* Ws[3] = {wt_l3, wt_r3, wt_sl3};
    const float* Bs[3] = {bl3_gs, br3_gs, bsl3};
    bf16_t* Ys[3] = {xl3, xr3, sl3};
    int Ms[3] = {NG, NS, NS};
    int Ns[3] = {256, 256, 64};
    int b0 = 0;
    for (int i = 0; i < 3; i++) {
      ga.X[i] = Xs[i]; ga.Wt[i] = Ws[i]; ga.Bv[i] = Bs[i]; ga.Y[i] = Ys[i];
      ga.M[i] = Ms[i]; ga.Ncol[i] = Ns[i]; ga.blk0[i] = b0;
      b0 += nrow(Ms[i], 64);
    }
    gemm_multi<3><<<b0, 256, 0, stream>>>(ga);   // 908 blocks
  }

  // ---- phase E: layer-3 gather (head-mean/self-loop/relu) -> d_out ----
  gatE<<<NS, 256, 0, stream>>>(rpc + NG, meta, We3_gs, att3_gs,
                               xl3, xr3, bo3_gs, sl3, (float*)d_out);
}

// Round 11
// 367.126 us; speedup vs baseline: 1.0461x; 1.0461x over previous
//
#include <hip/hip_runtime.h>
#include <cstdint>
#include <cstddef>

// Problem constants (match reference)
#define NS 4000
#define NG 50000
#define NE 250000
#define DIM 128
#define NDST_TOT (NG + NS)          // 54000 combined CSR rows (sg then gs)

typedef __bf16 bf16_t;
typedef bf16_t bf16x8 __attribute__((ext_vector_type(8)));
typedef bf16_t bf16x4 __attribute__((ext_vector_type(4)));
typedef float floatx4 __attribute__((ext_vector_type(4)));

template <int V> struct BV {};
template <> struct BV<2> { typedef bf16_t T __attribute__((ext_vector_type(2))); };
template <> struct BV<4> { typedef bf16_t T __attribute__((ext_vector_type(4))); };

// ---------------------------------------------------------------------------
// hist: per-dst degree counts for both relations (combined index space)
// ---------------------------------------------------------------------------
__global__ void hist2(const int* __restrict__ sgd, const int* __restrict__ gsd,
                      int* __restrict__ cnt) {
  int e = blockIdx.x * 256 + threadIdx.x;
  if (e >= NE) return;
  atomicAdd(cnt + sgd[e], 1);
  atomicAdd(cnt + NG + gsd[e], 1);
}

// ---------------------------------------------------------------------------
// 2-kernel parallel scan over n=54000 (53 blocks of 1024).
// NOTE: do NOT replace with a single-block serial-segment scan — measured
// 103 us (R8): per-thread serial global reads on one CU eat ~900-cyc
// cross-XCD misses. Parallel+coalesced is ~10 us total.
// ---------------------------------------------------------------------------
__global__ __launch_bounds__(1024) void scan1(const int* __restrict__ cnt,
                                              int* __restrict__ rp,
                                              int* __restrict__ csum, int n) {
  __shared__ int wsum[16];
  int i = blockIdx.x * 1024 + threadIdx.x;
  int lane = threadIdx.x & 63, w = threadIdx.x >> 6;
  int v = (i < n) ? cnt[i] : 0;
  int x = v;
#pragma unroll
  for (int off = 1; off < 64; off <<= 1) {
    int y = __shfl_up(x, off);
    if (lane >= off) x += y;
  }
  if (lane == 63) wsum[w] = x;
  __syncthreads();
  if (w == 0 && lane < 16) {
    int s = wsum[lane];
#pragma unroll
    for (int off = 1; off < 16; off <<= 1) {
      int y = __shfl_up(s, off);
      if (lane >= off) s += y;
    }
    wsum[lane] = s;
  }
  __syncthreads();
  int incl = x + (w ? wsum[w - 1] : 0);
  if (i < n) rp[i] = incl - v;
  if (threadIdx.x == 1023) csum[blockIdx.x] = incl;
}

__global__ __launch_bounds__(1024) void scan3(int* __restrict__ rp,
                                              const int* __restrict__ csum, int n) {
  __shared__ int pfx_s;
  if (threadIdx.x < 64) {
    int lane = threadIdx.x;
    int v = (lane < (int)blockIdx.x) ? csum[lane] : 0;   // blockIdx.x <= 52
#pragma unroll
    for (int off = 32; off > 0; off >>= 1) v += __shfl_down(v, off);
    if (lane == 0) pfx_s = v;
  }
  __syncthreads();
  int i = blockIdx.x * 1024 + threadIdx.x;
  if (i < n) rp[i] += pfx_s;
  if (i == 0) rp[n] = 2 * NE;                // static total sentinel
}

// ---------------------------------------------------------------------------
// Fused scatter + prep. Blocks [0, SCAT_B): CSR scatter of packed (src,ea)
// payloads. Blocks [SCAT_B, ...): 8 weight transposes (Wt[n][k]=bf16(W[k][n]))
// + bf16 casts of x_mrna / x_gene.
// ---------------------------------------------------------------------------
#define SCAT_B 1954                 // ceil(2*NE/256)
#define WT_TOT 143360               // 4*16384 + 2*32768 + 4096 + 8192
struct SPArgs {
  // scatter
  const int* sgd; const int* gsd; const int* sgs; const int* gss;
  const float* easg; const float* eags;
  const int* rp; int* cur; uint2* meta;
  // prep
  const float* W[8]; bf16_t* Wt[8]; int N[8]; int e0[8];
  const float* xm; bf16_t* xbm;
  const float* xg; bf16_t* xbg;
};

__global__ __launch_bounds__(256) void scatter_prep(SPArgs a) {
  if (blockIdx.x < SCAT_B) {
    int t = blockIdx.x * 256 + threadIdx.x;
    if (t < NE) {
      int d = a.sgd[t];
      int pos = atomicAdd(a.cur + d, 1);
      uint2 pv; pv.x = (unsigned)a.sgs[t]; pv.y = __float_as_uint(a.easg[t]);
      a.meta[a.rp[d] + pos] = pv;
    } else if (t < 2 * NE) {
      int e = t - NE;
      int d = a.gsd[e];
      int pos = atomicAdd(a.cur + NG + d, 1);
      uint2 pv; pv.x = (unsigned)a.gss[e]; pv.y = __float_as_uint(a.eags[e]);
      a.meta[a.rp[NG + d] + pos] = pv;
    }
  } else {
    int u = (blockIdx.x - SCAT_B) * 256 + threadIdx.x;
    if (u < WT_TOT) {
      int c = 0;
#pragma unroll
      for (int i = 1; i < 8; i++) if (u >= a.e0[i]) c = i;
      int idx = u - a.e0[c];
      int N = a.N[c];
      int k = idx / N, n = idx - k * N;
      a.Wt[c][n * 128 + k] = (bf16_t)a.W[c][idx];
    } else if (u < WT_TOT + 128000) {
      int j = (u - WT_TOT) * 4;
      float4 v = *reinterpret_cast<const float4*>(a.xm + j);
      bf16x4 b;
      b[0] = (bf16_t)v.x; b[1] = (bf16_t)v.y; b[2] = (bf16_t)v.z; b[3] = (bf16_t)v.w;
      *reinterpret_cast<bf16x4*>(a.xbm + j) = b;
    } else {
      int j = (u - WT_TOT - 128000) * 4;
      float4 v = *reinterpret_cast<const float4*>(a.xg + j);
      bf16x4 b;
      b[0] = (bf16_t)v.x; b[1] = (bf16_t)v.y; b[2] = (bf16_t)v.z; b[3] = (bf16_t)v.w;
      *reinterpret_cast<bf16x4*>(a.xbg + j) = b;
    }
  }
}

// ---------------------------------------------------------------------------
// Multi-config MFMA GEMM, runtime column count: Y = bf16(X @ W + b).
// X bf16 [M,128]; Wt bf16 [N][128]; N in {32,64,128,256}.
// C/D: col = lane&15, row = quad*4 + reg   (verified gfx950 mapping)
// ---------------------------------------------------------------------------
template <int NCFG>
struct GArgs {
  const bf16_t* X[NCFG];
  const bf16_t* Wt[NCFG];
  const float* Bv[NCFG];
  bf16_t* Y[NCFG];
  int M[NCFG];
  int Ncol[NCFG];
  int blk0[NCFG];
};

template <int NCFG>
__global__ __launch_bounds__(256) void gemm_multi(GArgs<NCFG> a) {
  int c = 0;
#pragma unroll
  for (int i = 1; i < NCFG; i++) if ((int)blockIdx.x >= a.blk0[i]) c = i;
  const bf16_t* X = a.X[c];
  const bf16_t* Wt = a.Wt[c];
  const float* B = a.Bv[c];
  bf16_t* Y = a.Y[c];
  int M = a.M[c];
  int N = a.Ncol[c];

  int wv = threadIdx.x >> 6, lane = threadIdx.x & 63;
  int m16 = lane & 15, quad = lane >> 4;
  int row0 = (blockIdx.x - a.blk0[c]) * 64 + wv * 16;
  int arow = row0 + m16;
  const bf16_t* xp = X + (size_t)arow * DIM + quad * 8;

  bf16x8 afrag[4];
#pragma unroll
  for (int kk = 0; kk < 4; kk++) {
    bf16x8 av = {};
    if (arow < M) av = *reinterpret_cast<const bf16x8*>(xp + kk * 32);
    afrag[kk] = av;
  }

  int ncols = N >> 4;
  for (int nt = 0; nt < ncols; nt++) {
    int col = nt * 16 + m16;
    const bf16_t* bptr = Wt + (size_t)col * DIM + quad * 8;
    floatx4 acc = {0.f, 0.f, 0.f, 0.f};
#pragma unroll
    for (int kk = 0; kk < 4; kk++) {
      bf16x8 b = *reinterpret_cast<const bf16x8*>(bptr + kk * 32);
      acc = __builtin_amdgcn_mfma_f32_16x16x32_bf16(afrag[kk], b, acc, 0, 0, 0);
    }
    float bias = B[col];
    int orow = row0 + quad * 4;
#pragma unroll
    for (int r = 0; r < 4; r++)
      if (orow + r < M) Y[(size_t)(orow + r) * N + col] = (bf16_t)(acc[r] + bias);
  }
}

// ---------------------------------------------------------------------------
// Fused phase-C gather.
// Blocks [0, SGB): sg relation, 4 waves/block, each wave FOUR dsts
//   (one rp 5-tuple + one metadata stage covers all 4; flag-weighted accs).
//   NOTE: do NOT convert the dst select to readfirstlane + scalar branch —
//   measured 73.4 us vs 55.6 us (R10): per-edge branches with 4x duplicated
//   shfl-chain bodies defeat the compiler's pipelining of the 8-edge group.
// Blocks [SGB, SGB+NS): gs relation, one block per dst, 4 subwaves, LDS comb.
// Both: C=32, VEC=2, bf16 in/out, fused bias(/sl)/relu epilogue.
// ---------------------------------------------------------------------------
#define SGB 3125                    // 50000 dsts / (4 waves * 4 dsts)
__global__ __launch_bounds__(256) void gatC(
    const int* __restrict__ rp, const uint2* __restrict__ meta,
    const float* __restrict__ WeS, const float* __restrict__ attS,
    const float* __restrict__ boS,
    const bf16_t* __restrict__ xlS, const bf16_t* __restrict__ xrS,
    bf16_t* __restrict__ outS,
    const float* __restrict__ WeG, const float* __restrict__ attG,
    const float* __restrict__ boG,
    const bf16_t* __restrict__ xlG, const bf16_t* __restrict__ xrG,
    const bf16_t* __restrict__ slG, bf16_t* __restrict__ outG) {
  typedef BV<2>::T bvec;
  __shared__ float lacc[4][128];
  __shared__ float lden[4][64];
  int wv = threadIdx.x >> 6, lane = threadIdx.x & 63;

  if (blockIdx.x < SGB) {
    // ---------------- sg: 4 dsts per wave ----------------
    int wid = blockIdx.x * 4 + wv;
    int d0 = wid * 4;
    int q = lane < 5 ? lane : 0;
    int rv = rp[d0 + q];
    int b0 = __shfl(rv, 0), m1 = __shfl(rv, 1), m2 = __shfl(rv, 2);
    int m3 = __shfl(rv, 3), e1 = __shfl(rv, 4);

    float2 wev = *reinterpret_cast<const float2*>(WeS + lane * 2);
    float2 atv = *reinterpret_cast<const float2*>(attS + lane * 2);
    float xrA[4][2];
#pragma unroll
    for (int r = 0; r < 4; r++) {
      bvec xb = *reinterpret_cast<const bvec*>(xrS + (size_t)(d0 + r) * 128 + lane * 2);
      xrA[r][0] = (float)xb[0]; xrA[r][1] = (float)xb[1];
    }
    float ac[4][2] = {};
    float dn[4] = {};

    for (int i0 = b0; i0 < e1; i0 += 64) {
      int cnt = min(64, e1 - i0);
      int s_l = 0; float ea_l = 0.f;
      if (lane < cnt) {
        uint2 mv = meta[i0 + lane];
        s_l = (int)mv.x; ea_l = __uint_as_float(mv.y);
      }
      for (int k0 = 0; k0 < cnt; k0 += 8) {
        int s8[8], gi[8]; float ea8[8];
        bvec raw[8];
#pragma unroll
        for (int g = 0; g < 8; g++) {
          int kk = (k0 + g < cnt) ? k0 + g : k0;
          s8[g] = __shfl(s_l, kk);
          ea8[g] = __shfl(ea_l, kk);
          gi[g] = i0 + kk;
        }
#pragma unroll
        for (int g = 0; g < 8; g++)
          raw[g] = *reinterpret_cast<const bvec*>(xlS + (size_t)s8[g] * 128 + lane * 2);
#pragma unroll
        for (int g = 0; g < 8; g++) {
          bool ge1 = gi[g] >= m1, ge2 = gi[g] >= m2, ge3 = gi[g] >= m3;
          float xs0 = ge2 ? (ge3 ? xrA[3][0] : xrA[2][0]) : (ge1 ? xrA[1][0] : xrA[0][0]);
          float xs1 = ge2 ? (ge3 ? xrA[3][1] : xrA[2][1]) : (ge1 ? xrA[1][1] : xrA[0][1]);
          float xf0 = (float)raw[g][0], xf1 = (float)raw[g][1];
          float m0 = xf0 + xs0 + ea8[g] * wev.x;
          float m1v = xf1 + xs1 + ea8[g] * wev.y;
          m0 = m0 > 0.f ? m0 : 0.2f * m0;      // leaky_relu(., 0.2)
          m1v = m1v > 0.f ? m1v : 0.2f * m1v;
          float p = fmaf(m0, atv.x, m1v * atv.y);
          p += __shfl_xor(p, 1);
          p += __shfl_xor(p, 2);
          p += __shfl_xor(p, 4);
          p += __shfl_xor(p, 8);               // head-wide logit
          float ex = __expf(p);
          if (k0 + g >= cnt) ex = 0.f;         // mask tail repeats
          int idx = (int)ge1 + (int)ge2 + (int)ge3;
#pragma unroll
          for (int r = 0; r < 4; r++) {
            float wr = (idx == r) ? ex : 0.f;
            dn[r] += wr;
            ac[r][0] = fmaf(wr, xf0, ac[r][0]);
            ac[r][1] = fmaf(wr, xf1, ac[r][1]);
          }
        }
      }
    }
    int j = lane * 2;
    float bo0 = boS[j], bo1 = boS[j + 1];
#pragma unroll
    for (int r = 0; r < 4; r++) {
      float iv = dn[r] > 0.f ? 1.f / dn[r] : 0.f;
      bvec o;
      o[0] = (bf16_t)fmaxf(ac[r][0] * iv + bo0, 0.f);
      o[1] = (bf16_t)fmaxf(ac[r][1] * iv + bo1, 0.f);
      *reinterpret_cast<bvec*>(outS + (size_t)(d0 + r) * 128 + j) = o;
    }
  } else {
    // ---------------- gs: one block per dst ----------------
    int d = blockIdx.x - SGB;
    const int* rpg = rp + NG;
    float2 wev = *reinterpret_cast<const float2*>(WeG + lane * 2);
    float2 atv = *reinterpret_cast<const float2*>(attG + lane * 2);
    bvec xrb = *reinterpret_cast<const bvec*>(xrG + (size_t)d * 128 + lane * 2);
    float xrv[2] = {(float)xrb[0], (float)xrb[1]};
    float acc[2] = {0.f, 0.f};
    float den = 0.f;

    int beg = rpg[d], end = rpg[d + 1];
    for (int i0 = beg + wv * 16; i0 < end; i0 += 64) {
      int cnt = min(16, end - i0);
      int s_l = 0; float ea_l = 0.f;
      if (lane < cnt) {
        uint2 mv = meta[i0 + lane];
        s_l = (int)mv.x; ea_l = __uint_as_float(mv.y);
      }
      for (int k0 = 0; k0 < cnt; k0 += 8) {
        int s8[8]; float ea8[8];
        bvec raw[8];
#pragma unroll
        for (int g = 0; g < 8; g++) {
          int kk = (k0 + g < cnt) ? k0 + g : k0;
          s8[g] = __shfl(s_l, kk);
          ea8[g] = __shfl(ea_l, kk);
        }
#pragma unroll
        for (int g = 0; g < 8; g++)
          raw[g] = *reinterpret_cast<const bvec*>(xlG + (size_t)s8[g] * 128 + lane * 2);
#pragma unroll
        for (int g = 0; g < 8; g++) {
          float xf0 = (float)raw[g][0], xf1 = (float)raw[g][1];
          float m0 = xf0 + xrv[0] + ea8[g] * wev.x;
          float m1v = xf1 + xrv[1] + ea8[g] * wev.y;
          m0 = m0 > 0.f ? m0 : 0.2f * m0;
          m1v = m1v > 0.f ? m1v : 0.2f * m1v;
          float p = fmaf(m0, atv.x, m1v * atv.y);
          p += __shfl_xor(p, 1);
          p += __shfl_xor(p, 2);
          p += __shfl_xor(p, 4);
          p += __shfl_xor(p, 8);
          float ex = __expf(p);
          if (k0 + g >= cnt) ex = 0.f;
          den += ex;
          acc[0] = fmaf(ex, xf0, acc[0]);
          acc[1] = fmaf(ex, xf1, acc[1]);
        }
      }
    }
    lacc[wv][lane * 2] = acc[0];
    lacc[wv][lane * 2 + 1] = acc[1];
    lden[wv][lane] = den;
    __syncthreads();
    if (wv != 0) return;
#pragma unroll
    for (int s = 1; s < 4; s++) {
      acc[0] += lacc[s][lane * 2];
      acc[1] += lacc[s][lane * 2 + 1];
      den += lden[s][lane];
    }
    float inv = den > 0.f ? 1.f / den : 0.f;
    int j = lane * 2;
    bvec o;
#pragma unroll
    for (int v = 0; v < 2; v++) {
      int jj = j + v;
      float val = acc[v] * inv + boG[jj] + (float)slG[(size_t)d * 32 + (jj & 31)];
      o[v] = (bf16_t)(val > 0.f ? val : 0.f);
    }
    *reinterpret_cast<bvec*>(outG + (size_t)d * 128 + j) = o;
  }
}

// ---------------------------------------------------------------------------
// Phase-E gather: one block per dst (4 subwaves, LDS combine), C=64, VEC=4.
// out fp32 = relu(mean_h(acc_h/den_h) + bo + sl)
// ---------------------------------------------------------------------------
__global__ __launch_bounds__(256) void gatE(
    const int* __restrict__ rp, const uint2* __restrict__ meta,
    const float* __restrict__ We, const float* __restrict__ att,
    const bf16_t* __restrict__ xl, const bf16_t* __restrict__ xr,
    const float* __restrict__ bo, const bf16_t* __restrict__ sl,
    float* __restrict__ out) {
  typedef BV<4>::T bvec;
  __shared__ float lacc[4][256];
  __shared__ float lden[4][64];
  int wv = threadIdx.x >> 6, lane = threadIdx.x & 63;
  int d = blockIdx.x;

  float wev[4], atv[4], xrv[4], acc[4];
  *reinterpret_cast<float4*>(wev) = *reinterpret_cast<const float4*>(We + lane * 4);
  *reinterpret_cast<float4*>(atv) = *reinterpret_cast<const float4*>(att + lane * 4);
  bvec xrb = *reinterpret_cast<const bvec*>(xr + (size_t)d * 256 + lane * 4);
#pragma unroll
  for (int v = 0; v < 4; v++) { xrv[v] = (float)xrb[v]; acc[v] = 0.f; }
  float den = 0.f;

  int beg = rp[d], end = rp[d + 1];
  for (int i0 = beg + wv * 16; i0 < end; i0 += 64) {
    int cnt = min(16, end - i0);
    int s_l = 0; float ea_l = 0.f;
    if (lane < cnt) {
      uint2 mv = meta[i0 + lane];
      s_l = (int)mv.x; ea_l = __uint_as_float(mv.y);
    }
    for (int k0 = 0; k0 < cnt; k0 += 8) {
      int s8[8]; float ea8[8];
      bvec raw[8];
#pragma unroll
      for (int g = 0; g < 8; g++) {
        int kk = (k0 + g < cnt) ? k0 + g : k0;
        s8[g] = __shfl(s_l, kk);
        ea8[g] = __shfl(ea_l, kk);
      }
#pragma unroll
      for (int g = 0; g < 8; g++)
        raw[g] = *reinterpret_cast<const bvec*>(xl + (size_t)s8[g] * 256 + lane * 4);
#pragma unroll
      for (int g = 0; g < 8; g++) {
        float xf[4];
        float p = 0.f;
#pragma unroll
        for (int v = 0; v < 4; v++) {
          xf[v] = (float)raw[g][v];
          float mm = xf[v] + xrv[v] + ea8[g] * wev[v];
          mm = mm > 0.f ? mm : 0.2f * mm;
          p = fmaf(mm, atv[v], p);
        }
        p += __shfl_xor(p, 1);
        p += __shfl_xor(p, 2);
        p += __shfl_xor(p, 4);
        p += __shfl_xor(p, 8);
        float ex = __expf(p);
        if (k0 + g >= cnt) ex = 0.f;
        den += ex;
#pragma unroll
        for (int v = 0; v < 4; v++) acc[v] = fmaf(ex, xf[v], acc[v]);
      }
    }
  }

#pragma unroll
  for (int v = 0; v < 4; v++) lacc[wv][lane * 4 + v] = acc[v];
  lden[wv][lane] = den;
  __syncthreads();
  if (wv != 0) return;
#pragma unroll
  for (int s = 1; s < 4; s++) {
#pragma unroll
    for (int v = 0; v < 4; v++) acc[v] += lacc[s][lane * 4 + v];
    den += lden[s][lane];
  }
  float inv = den > 0.f ? 1.f / den : 0.f;
#pragma unroll
  for (int v = 0; v < 4; v++) {
    float s_ = acc[v] * inv;
    s_ += __shfl_xor(s_, 16);
    s_ += __shfl_xor(s_, 32);                  // sum over the 4 heads
    if (lane < 16) {
      int c = (lane & 15) * 4 + v;
      float val = 0.25f * s_ + bo[c] + (float)sl[(size_t)d * 64 + c];
      out[(size_t)d * 64 + c] = val > 0.f ? val : 0.f;
    }
  }
}

// ---------------------------------------------------------------------------

static inline int nblk(long long threads) { return (int)((threads + 255) / 256); }
static inline int nrow(int M, int R) { return (M + R - 1) / R; }

extern "C" void kernel_launch(void* const* d_in, const int* in_sizes, int n_in,
                              void* d_out, int out_size, void* d_ws, size_t ws_size,
                              hipStream_t stream) {
  const float* x_mrna = (const float*)d_in[0];
  const float* x_gene = (const float*)d_in[1];
  const int* sg_src = (const int*)d_in[2];
  const int* sg_dst = (const int*)d_in[3];
  const int* gs_src = (const int*)d_in[4];
  const int* gs_dst = (const int*)d_in[5];
  const float* ea_sg = (const float*)d_in[6];
  const float* ea_gs = (const float*)d_in[7];
  const float* Wl1_sg = (const float*)d_in[8];
  const float* bl1_sg = (const float*)d_in[9];
  const float* Wr1_sg = (const float*)d_in[10];
  const float* br1_sg = (const float*)d_in[11];
  const float* We1_sg = (const float*)d_in[12];
  const float* att1_sg = (const float*)d_in[13];
  const float* bo1_sg = (const float*)d_in[14];
  const float* Wl1_gs = (const float*)d_in[15];
  const float* bl1_gs = (const float*)d_in[16];
  const float* Wr1_gs = (const float*)d_in[17];
  const float* br1_gs = (const float*)d_in[18];
  const float* We1_gs = (const float*)d_in[19];
  const float* att1_gs = (const float*)d_in[20];
  const float* bo1_gs = (const float*)d_in[21];
  const float* Wl3_gs = (const float*)d_in[22];
  const float* bl3_gs = (const float*)d_in[23];
  const float* Wr3_gs = (const float*)d_in[24];
  const float* br3_gs = (const float*)d_in[25];
  const float* We3_gs = (const float*)d_in[26];
  const float* att3_gs = (const float*)d_in[27];
  const float* bo3_gs = (const float*)d_in[28];
  const float* Wsl1 = (const float*)d_in[29];
  const float* bsl1 = (const float*)d_in[30];
  const float* Wsl3 = (const float*)d_in[31];
  const float* bsl3 = (const float*)d_in[32];

  // ---- workspace arena (fp32 element offsets), bf16 throughout ----
  float* ws = (float*)d_ws;
  bf16_t* xl1_gs = (bf16_t*)(ws + 0);        // bf16[50000*128] dead after C
  bf16_t* xl1_sg = (bf16_t*)(ws + 3200000);  // bf16[4000*128]  dead after C
  bf16_t* xr1_sg = (bf16_t*)(ws + 3456000);  // bf16[50000*128] dead after C
  bf16_t* xr1_gs = (bf16_t*)(ws + 6656000);  // bf16[4000*128]  dead after C
  bf16_t* xl3    = (bf16_t*)(ws + 0);        // bf16[50000*256] aliases [0,6.4M)
  bf16_t* xr3    = (bf16_t*)(ws + 6400000);  // bf16[4000*256]  aliases tail
  bf16_t* xb_mrna = (bf16_t*)(ws + 6912000); // bf16[4000*128]
  bf16_t* xb_gene = (bf16_t*)(ws + 7168000); // bf16[50000*128]
  bf16_t* x1_gene = (bf16_t*)(ws + 10368000);// bf16[50000*128]
  bf16_t* x1_mrna = (bf16_t*)(ws + 13568000);// bf16[4000*128]
  bf16_t* sl1    = (bf16_t*)(ws + 13824000); // bf16[4000*32]
  bf16_t* sl3    = (bf16_t*)(ws + 13856000); // bf16[4000*64]
  int*   ib      = (int*)(ws + 13920000);
  int* cnt  = ib + 0;                   // [54000] } zeroed together
  int* cur  = ib + 54000;               // [54000] }
  int* rpc  = ib + 108000;              // [54001]
  int* csum = ib + 162002;              // [64]
  uint2* meta = (uint2*)(ib + 162066);  // [500000] packed (src, ea), 8B-aligned
  bf16_t* wtb = (bf16_t*)(ib + 1162066);// [143360] bf16 transposed weights
  // end: ib + 1233746 ints -> total ~60.6 MB

  bf16_t* wt_l1sg = wtb + 0;
  bf16_t* wt_r1sg = wtb + 16384;
  bf16_t* wt_l1gs = wtb + 32768;
  bf16_t* wt_r1gs = wtb + 49152;
  bf16_t* wt_l3   = wtb + 65536;   // [256*128]
  bf16_t* wt_r3   = wtb + 98304;   // [256*128]
  bf16_t* wt_sl1  = wtb + 131072;  // [32*128]
  bf16_t* wt_sl3  = wtb + 135168;  // [64*128]

  // zero CSR counters (ws is poisoned 0xAA before every timed call)
  hipMemsetAsync(cnt, 0, 108000 * sizeof(int), stream);

  // ---- phase A: CSR build (parallel 2-kernel scan) ----
  hist2<<<nblk(NE), 256, 0, stream>>>(sg_dst, gs_dst, cnt);
  int nchunks = (NDST_TOT + 1023) / 1024;            // 53
  scan1<<<nchunks, 1024, 0, stream>>>(cnt, rpc, csum, NDST_TOT);
  scan3<<<nchunks, 1024, 0, stream>>>(rpc, csum, NDST_TOT);
  {
    SPArgs sa;
    sa.sgd = sg_dst; sa.gsd = gs_dst; sa.sgs = sg_src; sa.gss = gs_src;
    sa.easg = ea_sg; sa.eags = ea_gs; sa.rp = rpc; sa.cur = cur; sa.meta = meta;
    const float* Wsrc[8] = {Wl1_sg, Wr1_sg, Wl1_gs, Wr1_gs, Wl3_gs, Wr3_gs, Wsl1, Wsl3};
    bf16_t* Wdst[8] = {wt_l1sg, wt_r1sg, wt_l1gs, wt_r1gs, wt_l3, wt_r3, wt_sl1, wt_sl3};
    int Nn[8] = {128, 128, 128, 128, 256, 256, 32, 64};
    int e0[8] = {0, 16384, 32768, 49152, 65536, 98304, 131072, 135168};
    for (int i = 0; i < 8; i++) { sa.W[i] = Wsrc[i]; sa.Wt[i] = Wdst[i]; sa.N[i] = Nn[i]; sa.e0[i] = e0[i]; }
    sa.xm = x_mrna; sa.xbm = xb_mrna;
    sa.xg = x_gene; sa.xbg = xb_gene;
    scatter_prep<<<SCAT_B + 7310, 256, 0, stream>>>(sa);  // 9264 blocks
  }

  // ---- phase B: 5 fused layer-1 GEMMs (incl. sl1) ----
  {
    GArgs<5> ga;
    const bf16_t* Xs[5] = {xb_mrna, xb_gene, xb_gene, xb_mrna, xb_mrna};
    const bf16_t* Ws[5] = {wt_l1sg, wt_r1sg, wt_l1gs, wt_r1gs, wt_sl1};
    const float* Bs[5] = {bl1_sg, br1_sg, bl1_gs, br1_gs, bsl1};
    bf16_t* Ys[5] = {xl1_sg, xr1_sg, xl1_gs, xr1_gs, sl1};
    int Ms[5] = {NS, NG, NG, NS, NS};
    int Ns[5] = {128, 128, 128, 128, 32};
    int b0 = 0;
    for (int i = 0; i < 5; i++) {
      ga.X[i] = Xs[i]; ga.Wt[i] = Ws[i]; ga.Bv[i] = Bs[i]; ga.Y[i] = Ys[i];
      ga.M[i] = Ms[i]; ga.Ncol[i] = Ns[i]; ga.blk0[i] = b0;
      b0 += nrow(Ms[i], 64);
    }
    gemm_multi<5><<<b0, 256, 0, stream>>>(ga);   // 1753 blocks
  }

  // ---- phase C: fused layer-1 gathers (sg 4-dst waves + gs blocks) ----
  gatC<<<SGB + NS, 256, 0, stream>>>(
      rpc, meta,
      We1_sg, att1_sg, bo1_sg, xl1_sg, xr1_sg, x1_gene,
      We1_gs, att1_gs, bo1_gs, xl1_gs, xr1_gs, sl1, x1_mrna);

  // ---- phase D: 3 fused layer-3 GEMMs (incl. sl3) ----
  {
    GArgs<3> ga;
    const bf16_t* Xs[3] = {x1_gene, x1_mrna, x1_mrna};
    const bf16_t* Ws[3] = {wt_l3, wt_r3, wt_sl3};
    const float* Bs[3] = {bl3_gs, br3_gs, bsl3};
    bf16_t* Ys[3] = {xl3, xr3, sl3};
    int Ms[3] = {NG, NS, NS};
    int Ns[3] = {256, 256, 64};
    int b0 = 0;
    for (int i = 0; i < 3; i++) {
      ga.X[i] = Xs[i]; ga.Wt[i] = Ws[i]; ga.Bv[i] = Bs[i]; ga.Y[i] = Ys[i];
      ga.M[i] = Ms[i]; ga.Ncol[i] = Ns[i]; ga.blk0[i] = b0;
      b0 += nrow(Ms[i], 64);
    }
    gemm_multi<3><<<b0, 256, 0, stream>>>(ga);   // 908 blocks
  }

  // ---- phase E: layer-3 gather (head-mean/self-loop/relu) -> d_out ----
  gatE<<<NS, 256, 0, stream>>>(rpc + NG, meta, We3_gs, att3_gs,
                               xl3, xr3, bo3_gs, sl3, (float*)d_out);
}

// Round 12
// 341.371 us; speedup vs baseline: 1.1250x; 1.0754x over previous
//
#include <hip/hip_runtime.h>
#include <cstdint>
#include <cstddef>

// Problem constants (match reference)
#define NS 4000
#define NG 50000
#define NE 250000
#define DIM 128
#define NDST_TOT (NG + NS)          // 54000 combined CSR rows (sg then gs)

typedef __bf16 bf16_t;
typedef bf16_t bf16x8 __attribute__((ext_vector_type(8)));
typedef bf16_t bf16x4 __attribute__((ext_vector_type(4)));
typedef bf16_t bf16x2 __attribute__((ext_vector_type(2)));
typedef float floatx4 __attribute__((ext_vector_type(4)));

// ---------------------------------------------------------------------------
// hist: per-dst degree counts for both relations (combined index space)
// ---------------------------------------------------------------------------
__global__ void hist2(const int* __restrict__ sgd, const int* __restrict__ gsd,
                      int* __restrict__ cnt) {
  int e = blockIdx.x * 256 + threadIdx.x;
  if (e >= NE) return;
  atomicAdd(cnt + sgd[e], 1);
  atomicAdd(cnt + NG + gsd[e], 1);
}

// ---------------------------------------------------------------------------
// 2-kernel parallel scan over n=54000 (53 blocks of 1024).
// NOTE: do NOT replace with a single-block serial-segment scan — measured
// 103 us (R8): per-thread serial global reads on one CU eat ~900-cyc
// cross-XCD misses. Parallel+coalesced is ~10 us total.
// ---------------------------------------------------------------------------
__global__ __launch_bounds__(1024) void scan1(const int* __restrict__ cnt,
                                              int* __restrict__ rp,
                                              int* __restrict__ csum, int n) {
  __shared__ int wsum[16];
  int i = blockIdx.x * 1024 + threadIdx.x;
  int lane = threadIdx.x & 63, w = threadIdx.x >> 6;
  int v = (i < n) ? cnt[i] : 0;
  int x = v;
#pragma unroll
  for (int off = 1; off < 64; off <<= 1) {
    int y = __shfl_up(x, off);
    if (lane >= off) x += y;
  }
  if (lane == 63) wsum[w] = x;
  __syncthreads();
  if (w == 0 && lane < 16) {
    int s = wsum[lane];
#pragma unroll
    for (int off = 1; off < 16; off <<= 1) {
      int y = __shfl_up(s, off);
      if (lane >= off) s += y;
    }
    wsum[lane] = s;
  }
  __syncthreads();
  int incl = x + (w ? wsum[w - 1] : 0);
  if (i < n) rp[i] = incl - v;
  if (threadIdx.x == 1023) csum[blockIdx.x] = incl;
}

__global__ __launch_bounds__(1024) void scan3(int* __restrict__ rp,
                                              const int* __restrict__ csum, int n) {
  __shared__ int pfx_s;
  if (threadIdx.x < 64) {
    int lane = threadIdx.x;
    int v = (lane < (int)blockIdx.x) ? csum[lane] : 0;   // blockIdx.x <= 52
#pragma unroll
    for (int off = 32; off > 0; off >>= 1) v += __shfl_down(v, off);
    if (lane == 0) pfx_s = v;
  }
  __syncthreads();
  int i = blockIdx.x * 1024 + threadIdx.x;
  if (i < n) rp[i] += pfx_s;
  if (i == 0) rp[n] = 2 * NE;                // static total sentinel
}

// ---------------------------------------------------------------------------
// Fused scatter + prep. Blocks [0, SCAT_B): CSR scatter of packed (src,ea)
// payloads. Blocks [SCAT_B, ...): 8 weight transposes (Wt[n][k]=bf16(W[k][n]))
// + bf16 casts of x_mrna / x_gene.
// ---------------------------------------------------------------------------
#define SCAT_B 1954                 // ceil(2*NE/256)
#define WT_TOT 143360               // 4*16384 + 2*32768 + 4096 + 8192
struct SPArgs {
  // scatter
  const int* sgd; const int* gsd; const int* sgs; const int* gss;
  const float* easg; const float* eags;
  const int* rp; int* cur; uint2* meta;
  // prep
  const float* W[8]; bf16_t* Wt[8]; int N[8]; int e0[8];
  const float* xm; bf16_t* xbm;
  const float* xg; bf16_t* xbg;
};

__global__ __launch_bounds__(256) void scatter_prep(SPArgs a) {
  if (blockIdx.x < SCAT_B) {
    int t = blockIdx.x * 256 + threadIdx.x;
    if (t < NE) {
      int d = a.sgd[t];
      int pos = atomicAdd(a.cur + d, 1);
      uint2 pv; pv.x = (unsigned)a.sgs[t]; pv.y = __float_as_uint(a.easg[t]);
      a.meta[a.rp[d] + pos] = pv;
    } else if (t < 2 * NE) {
      int e = t - NE;
      int d = a.gsd[e];
      int pos = atomicAdd(a.cur + NG + d, 1);
      uint2 pv; pv.x = (unsigned)a.gss[e]; pv.y = __float_as_uint(a.eags[e]);
      a.meta[a.rp[NG + d] + pos] = pv;
    }
  } else {
    int u = (blockIdx.x - SCAT_B) * 256 + threadIdx.x;
    if (u < WT_TOT) {
      int c = 0;
#pragma unroll
      for (int i = 1; i < 8; i++) if (u >= a.e0[i]) c = i;
      int idx = u - a.e0[c];
      int N = a.N[c];
      int k = idx / N, n = idx - k * N;
      a.Wt[c][n * 128 + k] = (bf16_t)a.W[c][idx];
    } else if (u < WT_TOT + 128000) {
      int j = (u - WT_TOT) * 4;
      float4 v = *reinterpret_cast<const float4*>(a.xm + j);
      bf16x4 b;
      b[0] = (bf16_t)v.x; b[1] = (bf16_t)v.y; b[2] = (bf16_t)v.z; b[3] = (bf16_t)v.w;
      *reinterpret_cast<bf16x4*>(a.xbm + j) = b;
    } else {
      int j = (u - WT_TOT - 128000) * 4;
      float4 v = *reinterpret_cast<const float4*>(a.xg + j);
      bf16x4 b;
      b[0] = (bf16_t)v.x; b[1] = (bf16_t)v.y; b[2] = (bf16_t)v.z; b[3] = (bf16_t)v.w;
      *reinterpret_cast<bf16x4*>(a.xbg + j) = b;
    }
  }
}

// ---------------------------------------------------------------------------
// Multi-config MFMA GEMM, runtime column count: Y = bf16(X @ W + b).
// ---------------------------------------------------------------------------
template <int NCFG>
struct GArgs {
  const bf16_t* X[NCFG];
  const bf16_t* Wt[NCFG];
  const float* Bv[NCFG];
  bf16_t* Y[NCFG];
  int M[NCFG];
  int Ncol[NCFG];
  int blk0[NCFG];
};

template <int NCFG>
__global__ __launch_bounds__(256) void gemm_multi(GArgs<NCFG> a) {
  int c = 0;
#pragma unroll
  for (int i = 1; i < NCFG; i++) if ((int)blockIdx.x >= a.blk0[i]) c = i;
  const bf16_t* X = a.X[c];
  const bf16_t* Wt = a.Wt[c];
  const float* B = a.Bv[c];
  bf16_t* Y = a.Y[c];
  int M = a.M[c];
  int N = a.Ncol[c];

  int wv = threadIdx.x >> 6, lane = threadIdx.x & 63;
  int m16 = lane & 15, quad = lane >> 4;
  int row0 = (blockIdx.x - a.blk0[c]) * 64 + wv * 16;
  int arow = row0 + m16;
  const bf16_t* xp = X + (size_t)arow * DIM + quad * 8;

  bf16x8 afrag[4];
#pragma unroll
  for (int kk = 0; kk < 4; kk++) {
    bf16x8 av = {};
    if (arow < M) av = *reinterpret_cast<const bf16x8*>(xp + kk * 32);
    afrag[kk] = av;
  }

  int ncols = N >> 4;
  for (int nt = 0; nt < ncols; nt++) {
    int col = nt * 16 + m16;
    const bf16_t* bptr = Wt + (size_t)col * DIM + quad * 8;
    floatx4 acc = {0.f, 0.f, 0.f, 0.f};
#pragma unroll
    for (int kk = 0; kk < 4; kk++) {
      bf16x8 b = *reinterpret_cast<const bf16x8*>(bptr + kk * 32);
      acc = __builtin_amdgcn_mfma_f32_16x16x32_bf16(afrag[kk], b, acc, 0, 0, 0);
    }
    float bias = B[col];
    int orow = row0 + quad * 4;
#pragma unroll
    for (int r = 0; r < 4; r++)
      if (orow + r < M) Y[(size_t)(orow + r) * N + col] = (bf16_t)(acc[r] + bias);
  }
}

// ---------------------------------------------------------------------------
// Fused phase-C gather, GROUP-PER-DST layout (NC=128, 8 ch per lane,
// 16-lane groups; head = gl>>2 -> logit reduce = 2 shfls, no dst select).
// Blocks [0, SGB): sg — 4 waves/block, each wave 4 dsts, one per group.
// Blocks [SGB, SGB+NS): gs — one block per dst; 16 groups walk LDS-staged
//   edges (block-coalesced meta stage), partials combined in LDS.
// NOTE: do NOT use readfirstlane+scalar branch per edge (R10: 73 us vs 55);
// this layout removes the select entirely instead.
// ---------------------------------------------------------------------------
#define SGB 3125                    // 50000 dsts / (4 waves * 4 dsts)
__global__ __launch_bounds__(256) void gatC(
    const int* __restrict__ rp, const uint2* __restrict__ meta,
    const float* __restrict__ WeS, const float* __restrict__ attS,
    const float* __restrict__ boS,
    const bf16_t* __restrict__ xlS, const bf16_t* __restrict__ xrS,
    bf16_t* __restrict__ outS,
    const float* __restrict__ WeG, const float* __restrict__ attG,
    const float* __restrict__ boG,
    const bf16_t* __restrict__ xlG, const bf16_t* __restrict__ xrG,
    const bf16_t* __restrict__ slG, bf16_t* __restrict__ outG) {
  __shared__ uint2 smeta[256];
  __shared__ float lacc[16][128];
  __shared__ float lden[16][4];
  int lane = threadIdx.x & 63, wv = threadIdx.x >> 6;
  int gl = lane & 15, grp = lane >> 4;

  if (blockIdx.x < SGB) {
    // ---------------- sg: 4 dsts per wave, one per 16-lane group ----------
    int wid = blockIdx.x * 4 + wv;
    int d0 = wid * 4;
    int q = lane < 5 ? lane : 0;
    int rv = rp[d0 + q];
    int beg = __shfl(rv, grp), end = __shfl(rv, grp + 1);
    int dst = d0 + grp;

    float wev[8], atv[8], xrv[8], acc[8];
    *reinterpret_cast<float4*>(wev) = *reinterpret_cast<const float4*>(WeS + gl * 8);
    *reinterpret_cast<float4*>(wev + 4) = *reinterpret_cast<const float4*>(WeS + gl * 8 + 4);
    *reinterpret_cast<float4*>(atv) = *reinterpret_cast<const float4*>(attS + gl * 8);
    *reinterpret_cast<float4*>(atv + 4) = *reinterpret_cast<const float4*>(attS + gl * 8 + 4);
    bf16x8 xrb = *reinterpret_cast<const bf16x8*>(xrS + (size_t)dst * 128 + gl * 8);
#pragma unroll
    for (int v = 0; v < 8; v++) { xrv[v] = (float)xrb[v]; acc[v] = 0.f; }
    float den = 0.f;

    for (int i0 = beg; i0 < end; i0 += 16) {
      int cnt = min(16, end - i0);
      int s_l = 0; float ea_l = 0.f;
      if (gl < cnt) {
        uint2 mv = meta[i0 + gl];
        s_l = (int)mv.x; ea_l = __uint_as_float(mv.y);
      }
      // 1-deep prefetch of next edge's row
      int base = lane & 48;
      float ea = __shfl(ea_l, base);
      bf16x8 xlb = *reinterpret_cast<const bf16x8*>(
          xlS + (size_t)__shfl(s_l, base) * 128 + gl * 8);
      for (int k = 0; k < cnt; k++) {
        bf16x8 cur = xlb;
        float eac = ea;
        if (k + 1 < cnt) {
          ea = __shfl(ea_l, base + k + 1);
          xlb = *reinterpret_cast<const bf16x8*>(
              xlS + (size_t)__shfl(s_l, base + k + 1) * 128 + gl * 8);
        }
        float p = 0.f, xf[8];
#pragma unroll
        for (int v = 0; v < 8; v++) {
          xf[v] = (float)cur[v];
          float z = fmaf(eac, wev[v], xrv[v]) + xf[v];
          z = z > 0.f ? z : 0.2f * z;            // leaky_relu(., 0.2)
          p = fmaf(z, atv[v], p);
        }
        p += __shfl_xor(p, 1);
        p += __shfl_xor(p, 2);                   // head-wide logit (4 lanes)
        float ex = __expf(p);
        den += ex;
#pragma unroll
        for (int v = 0; v < 8; v++) acc[v] = fmaf(ex, xf[v], acc[v]);
      }
    }
    float inv = den > 0.f ? 1.f / den : 0.f;
    bf16x8 o;
#pragma unroll
    for (int v = 0; v < 8; v++) {
      float val = acc[v] * inv + boS[gl * 8 + v];
      o[v] = (bf16_t)(val > 0.f ? val : 0.f);
    }
    *reinterpret_cast<bf16x8*>(outS + (size_t)dst * 128 + gl * 8) = o;
  } else {
    // ---------------- gs: one block per dst, 16 groups over LDS stage -----
    int d = (int)blockIdx.x - SGB;
    const int* rpg = rp + NG;
    int G = wv * 4 + grp;
    int tid = threadIdx.x;

    float wev[8], atv[8], xrv[8], acc[8];
    *reinterpret_cast<float4*>(wev) = *reinterpret_cast<const float4*>(WeG + gl * 8);
    *reinterpret_cast<float4*>(wev + 4) = *reinterpret_cast<const float4*>(WeG + gl * 8 + 4);
    *reinterpret_cast<float4*>(atv) = *reinterpret_cast<const float4*>(attG + gl * 8);
    *reinterpret_cast<float4*>(atv + 4) = *reinterpret_cast<const float4*>(attG + gl * 8 + 4);
    bf16x8 xrb = *reinterpret_cast<const bf16x8*>(xrG + (size_t)d * 128 + gl * 8);
#pragma unroll
    for (int v = 0; v < 8; v++) { xrv[v] = (float)xrb[v]; acc[v] = 0.f; }
    float den = 0.f;

    int beg = rpg[d], end = rpg[d + 1];
    for (int base = beg; base < end; base += 256) {
      int cntb = min(256, end - base);
      __syncthreads();
      if (tid < cntb) smeta[tid] = meta[base + tid];
      __syncthreads();
      int e = G;
      uint2 mv; bf16x8 xlb;
      if (e < cntb) {
        mv = smeta[e];
        xlb = *reinterpret_cast<const bf16x8*>(xlG + (size_t)mv.x * 128 + gl * 8);
      }
      while (e < cntb) {
        bf16x8 cur = xlb;
        float eac = __uint_as_float(mv.y);
        int en = e + 16;
        if (en < cntb) {
          mv = smeta[en];
          xlb = *reinterpret_cast<const bf16x8*>(xlG + (size_t)mv.x * 128 + gl * 8);
        }
        float p = 0.f, xf[8];
#pragma unroll
        for (int v = 0; v < 8; v++) {
          xf[v] = (float)cur[v];
          float z = fmaf(eac, wev[v], xrv[v]) + xf[v];
          z = z > 0.f ? z : 0.2f * z;
          p = fmaf(z, atv[v], p);
        }
        p += __shfl_xor(p, 1);
        p += __shfl_xor(p, 2);
        float ex = __expf(p);
        den += ex;
#pragma unroll
        for (int v = 0; v < 8; v++) acc[v] = fmaf(ex, xf[v], acc[v]);
        e = en;
      }
    }
#pragma unroll
    for (int v = 0; v < 8; v++) lacc[G][gl * 8 + v] = acc[v];
    if ((gl & 3) == 0) lden[G][gl >> 2] = den;
    __syncthreads();
    if (wv != 0) return;
    int ch = lane * 2;
    int h = lane >> 4;
    float a0 = 0.f, a1 = 0.f, dh = 0.f;
#pragma unroll
    for (int g2 = 0; g2 < 16; g2++) {
      a0 += lacc[g2][ch];
      a1 += lacc[g2][ch + 1];
      dh += lden[g2][h];
    }
    float inv = dh > 0.f ? 1.f / dh : 0.f;
    float v0 = a0 * inv + boG[ch] + (float)slG[(size_t)d * 32 + (ch & 31)];
    float v1 = a1 * inv + boG[ch + 1] + (float)slG[(size_t)d * 32 + ((ch + 1) & 31)];
    bf16x2 o;
    o[0] = (bf16_t)(v0 > 0.f ? v0 : 0.f);
    o[1] = (bf16_t)(v1 > 0.f ? v1 : 0.f);
    *reinterpret_cast<bf16x2*>(outG + (size_t)d * 128 + ch) = o;
  }
}

// ---------------------------------------------------------------------------
// Phase-E gather: one block per dst; 16 groups of 16 lanes, 16 ch/lane
// (NC=256); LDS-staged edges + LDS combine; head-mean epilogue -> fp32 out.
// ---------------------------------------------------------------------------
__global__ __launch_bounds__(256) void gatE(
    const int* __restrict__ rp, const uint2* __restrict__ meta,
    const float* __restrict__ We, const float* __restrict__ att,
    const bf16_t* __restrict__ xl, const bf16_t* __restrict__ xr,
    const float* __restrict__ bo, const bf16_t* __restrict__ sl,
    float* __restrict__ out) {
  __shared__ uint2 smeta[256];
  __shared__ float lacc[16][256];
  __shared__ float lden[16][4];
  int lane = threadIdx.x & 63, wv = threadIdx.x >> 6;
  int gl = lane & 15, grp = lane >> 4;
  int G = wv * 4 + grp;
  int tid = threadIdx.x;
  int d = blockIdx.x;

  float wev[16], atv[16], xrv[16], acc[16];
#pragma unroll
  for (int b = 0; b < 4; b++) {
    *reinterpret_cast<float4*>(wev + b * 4) =
        *reinterpret_cast<const float4*>(We + gl * 16 + b * 4);
    *reinterpret_cast<float4*>(atv + b * 4) =
        *reinterpret_cast<const float4*>(att + gl * 16 + b * 4);
  }
  {
    bf16x8 r0 = *reinterpret_cast<const bf16x8*>(xr + (size_t)d * 256 + gl * 16);
    bf16x8 r1 = *reinterpret_cast<const bf16x8*>(xr + (size_t)d * 256 + gl * 16 + 8);
#pragma unroll
    for (int v = 0; v < 8; v++) { xrv[v] = (float)r0[v]; xrv[v + 8] = (float)r1[v]; }
  }
#pragma unroll
  for (int v = 0; v < 16; v++) acc[v] = 0.f;
  float den = 0.f;

  int beg = rp[d], end = rp[d + 1];
  for (int base = beg; base < end; base += 256) {
    int cntb = min(256, end - base);
    __syncthreads();
    if (tid < cntb) smeta[tid] = meta[base + tid];
    __syncthreads();
    int e = G;
    uint2 mv; bf16x8 x0, x1;
    if (e < cntb) {
      mv = smeta[e];
      x0 = *reinterpret_cast<const bf16x8*>(xl + (size_t)mv.x * 256 + gl * 16);
      x1 = *reinterpret_cast<const bf16x8*>(xl + (size_t)mv.x * 256 + gl * 16 + 8);
    }
    while (e < cntb) {
      bf16x8 c0 = x0, c1 = x1;
      float eac = __uint_as_float(mv.y);
      int en = e + 16;
      if (en < cntb) {
        mv = smeta[en];
        x0 = *reinterpret_cast<const bf16x8*>(xl + (size_t)mv.x * 256 + gl * 16);
        x1 = *reinterpret_cast<const bf16x8*>(xl + (size_t)mv.x * 256 + gl * 16 + 8);
      }
      float p = 0.f, xf[16];
#pragma unroll
      for (int v = 0; v < 8; v++) { xf[v] = (float)c0[v]; xf[v + 8] = (float)c1[v]; }
#pragma unroll
      for (int v = 0; v < 16; v++) {
        float z = fmaf(eac, wev[v], xrv[v]) + xf[v];
        z = z > 0.f ? z : 0.2f * z;              // leaky_relu(., 0.2)
        p = fmaf(z, atv[v], p);
      }
      p += __shfl_xor(p, 1);
      p += __shfl_xor(p, 2);                     // head-wide logit (4 lanes)
      float ex = __expf(p);
      den += ex;
#pragma unroll
      for (int v = 0; v < 16; v++) acc[v] = fmaf(ex, xf[v], acc[v]);
      e = en;
    }
  }
#pragma unroll
  for (int v = 0; v < 16; v++) lacc[G][gl * 16 + v] = acc[v];
  if ((gl & 3) == 0) lden[G][gl >> 2] = den;
  __syncthreads();
  if (wv != 0) return;
  int ch = lane * 4;
  int h = lane >> 4;
  float a[4] = {0.f, 0.f, 0.f, 0.f};
  float dh = 0.f;
#pragma unroll
  for (int g2 = 0; g2 < 16; g2++) {
#pragma unroll
    for (int v = 0; v < 4; v++) a[v] += lacc[g2][ch + v];
    dh += lden[g2][h];
  }
  float inv = dh > 0.f ? 1.f / dh : 0.f;
#pragma unroll
  for (int v = 0; v < 4; v++) {
    float s_ = a[v] * inv;
    s_ += __shfl_xor(s_, 16);
    s_ += __shfl_xor(s_, 32);                    // sum over the 4 heads
    if (lane < 16) {
      int c = (lane & 15) * 4 + v;
      float val = 0.25f * s_ + bo[c] + (float)sl[(size_t)d * 64 + c];
      out[(size_t)d * 64 + c] = val > 0.f ? val : 0.f;
    }
  }
}

// ---------------------------------------------------------------------------

static inline int nblk(long long threads) { return (int)((threads + 255) / 256); }
static inline int nrow(int M, int R) { return (M + R - 1) / R; }

extern "C" void kernel_launch(void* const* d_in, const int* in_sizes, int n_in,
                              void* d_out, int out_size, void* d_ws, size_t ws_size,
                              hipStream_t stream) {
  const float* x_mrna = (const float*)d_in[0];
  const float* x_gene = (const float*)d_in[1];
  const int* sg_src = (const int*)d_in[2];
  const int* sg_dst = (const int*)d_in[3];
  const int* gs_src = (const int*)d_in[4];
  const int* gs_dst = (const int*)d_in[5];
  const float* ea_sg = (const float*)d_in[6];
  const float* ea_gs = (const float*)d_in[7];
  const float* Wl1_sg = (const float*)d_in[8];
  const float* bl1_sg = (const float*)d_in[9];
  const float* Wr1_sg = (const float*)d_in[10];
  const float* br1_sg = (const float*)d_in[11];
  const float* We1_sg = (const float*)d_in[12];
  const float* att1_sg = (const float*)d_in[13];
  const float* bo1_sg = (const float*)d_in[14];
  const float* Wl1_gs = (const float*)d_in[15];
  const float* bl1_gs = (const float*)d_in[16];
  const float* Wr1_gs = (const float*)d_in[17];
  const float* br1_gs = (const float*)d_in[18];
  const float* We1_gs = (const float*)d_in[19];
  const float* att1_gs = (const float*)d_in[20];
  const float* bo1_gs = (const float*)d_in[21];
  const float* Wl3_gs = (const float*)d_in[22];
  const float* bl3_gs = (const float*)d_in[23];
  const float* Wr3_gs = (const float*)d_in[24];
  const float* br3_gs = (const float*)d_in[25];
  const float* We3_gs = (const float*)d_in[26];
  const float* att3_gs = (const float*)d_in[27];
  const float* bo3_gs = (const float*)d_in[28];
  const float* Wsl1 = (const float*)d_in[29];
  const float* bsl1 = (const float*)d_in[30];
  const float* Wsl3 = (const float*)d_in[31];
  const float* bsl3 = (const float*)d_in[32];

  // ---- workspace arena (fp32 element offsets), bf16 throughout ----
  float* ws = (float*)d_ws;
  bf16_t* xl1_gs = (bf16_t*)(ws + 0);        // bf16[50000*128] dead after C
  bf16_t* xl1_sg = (bf16_t*)(ws + 3200000);  // bf16[4000*128]  dead after C
  bf16_t* xr1_sg = (bf16_t*)(ws + 3456000);  // bf16[50000*128] dead after C
  bf16_t* xr1_gs = (bf16_t*)(ws + 6656000);  // bf16[4000*128]  dead after C
  bf16_t* xl3    = (bf16_t*)(ws + 0);        // bf16[50000*256] aliases [0,6.4M)
  bf16_t* xr3    = (bf16_t*)(ws + 6400000);  // bf16[4000*256]  aliases tail
  bf16_t* xb_mrna = (bf16_t*)(ws + 6912000); // bf16[4000*128]
  bf16_t* xb_gene = (bf16_t*)(ws + 7168000); // bf16[50000*128]
  bf16_t* x1_gene = (bf16_t*)(ws + 10368000);// bf16[50000*128]
  bf16_t* x1_mrna = (bf16_t*)(ws + 13568000);// bf16[4000*128]
  bf16_t* sl1    = (bf16_t*)(ws + 13824000); // bf16[4000*32]
  bf16_t* sl3    = (bf16_t*)(ws + 13856000); // bf16[4000*64]
  int*   ib      = (int*)(ws + 13920000);
  int* cnt  = ib + 0;                   // [54000] } zeroed together
  int* cur  = ib + 54000;               // [54000] }
  int* rpc  = ib + 108000;              // [54001]
  int* csum = ib + 162002;              // [64]
  uint2* meta = (uint2*)(ib + 162066);  // [500000] packed (src, ea), 8B-aligned
  bf16_t* wtb = (bf16_t*)(ib + 1162066);// [143360] bf16 transposed weights
  // end: ib + 1233746 ints -> total ~60.6 MB

  bf16_t* wt_l1sg = wtb + 0;
  bf16_t* wt_r1sg = wtb + 16384;
  bf16_t* wt_l1gs = wtb + 32768;
  bf16_t* wt_r1gs = wtb + 49152;
  bf16_t* wt_l3   = wtb + 65536;   // [256*128]
  bf16_t* wt_r3   = wtb + 98304;   // [256*128]
  bf16_t* wt_sl1  = wtb + 131072;  // [32*128]
  bf16_t* wt_sl3  = wtb + 135168;  // [64*128]

  // zero CSR counters (ws is poisoned 0xAA before every timed call)
  hipMemsetAsync(cnt, 0, 108000 * sizeof(int), stream);

  // ---- phase A: CSR build (parallel 2-kernel scan) ----
  hist2<<<nblk(NE), 256, 0, stream>>>(sg_dst, gs_dst, cnt);
  int nchunks = (NDST_TOT + 1023) / 1024;            // 53
  scan1<<<nchunks, 1024, 0, stream>>>(cnt, rpc, csum, NDST_TOT);
  scan3<<<nchunks, 1024, 0, stream>>>(rpc, csum, NDST_TOT);
  {
    SPArgs sa;
    sa.sgd = sg_dst; sa.gsd = gs_dst; sa.sgs = sg_src; sa.gss = gs_src;
    sa.easg = ea_sg; sa.eags = ea_gs; sa.rp = rpc; sa.cur = cur; sa.meta = meta;
    const float* Wsrc[8] = {Wl1_sg, Wr1_sg, Wl1_gs, Wr1_gs, Wl3_gs, Wr3_gs, Wsl1, Wsl3};
    bf16_t* Wdst[8] = {wt_l1sg, wt_r1sg, wt_l1gs, wt_r1gs, wt_l3, wt_r3, wt_sl1, wt_sl3};
    int Nn[8] = {128, 128, 128, 128, 256, 256, 32, 64};
    int e0[8] = {0, 16384, 32768, 49152, 65536, 98304, 131072, 135168};
    for (int i = 0; i < 8; i++) { sa.W[i] = Wsrc[i]; sa.Wt[i] = Wdst[i]; sa.N[i] = Nn[i]; sa.e0[i] = e0[i]; }
    sa.xm = x_mrna; sa.xbm = xb_mrna;
    sa.xg = x_gene; sa.xbg = xb_gene;
    scatter_prep<<<SCAT_B + 7310, 256, 0, stream>>>(sa);  // 9264 blocks
  }

  // ---- phase B: 5 fused layer-1 GEMMs (incl. sl1) ----
  {
    GArgs<5> ga;
    const bf16_t* Xs[5] = {xb_mrna, xb_gene, xb_gene, xb_mrna, xb_mrna};
    const bf16_t* Ws[5] = {wt_l1sg, wt_r1sg, wt_l1gs, wt_r1gs, wt_sl1};
    const float* Bs[5] = {bl1_sg, br1_sg, bl1_gs, br1_gs, bsl1};
    bf16_t* Ys[5] = {xl1_sg, xr1_sg, xl1_gs, xr1_gs, sl1};
    int Ms[5] = {NS, NG, NG, NS, NS};
    int Ns[5] = {128, 128, 128, 128, 32};
    int b0 = 0;
    for (int i = 0; i < 5; i++) {
      ga.X[i] = Xs[i]; ga.Wt[i] = Ws[i]; ga.Bv[i] = Bs[i]; ga.Y[i] = Ys[i];
      ga.M[i] = Ms[i]; ga.Ncol[i] = Ns[i]; ga.blk0[i] = b0;
      b0 += nrow(Ms[i], 64);
    }
    gemm_multi<5><<<b0, 256, 0, stream>>>(ga);   // 1753 blocks
  }

  // ---- phase C: fused layer-1 gathers ----
  gatC<<<SGB + NS, 256, 0, stream>>>(
      rpc, meta,
      We1_sg, att1_sg, bo1_sg, xl1_sg, xr1_sg, x1_gene,
      We1_gs, att1_gs, bo1_gs, xl1_gs, xr1_gs, sl1, x1_mrna);

  // ---- phase D: 3 fused layer-3 GEMMs (incl. sl3) ----
  {
    GArgs<3> ga;
    const bf16_t* Xs[3] = {x1_gene, x1_mrna, x1_mrna};
    const bf16_t* Ws[3] = {wt_l3, wt_r3, wt_sl3};
    const float* Bs[3] = {bl3_gs, br3_gs, bsl3};
    bf16_t* Ys[3] = {xl3, xr3, sl3};
    int Ms[3] = {NG, NS, NS};
    int Ns[3] = {256, 256, 64};
    int b0 = 0;
    for (int i = 0; i < 3; i++) {
      ga.X[i] = Xs[i]; ga.Wt[i] = Ws[i]; ga.Bv[i] = Bs[i]; ga.Y[i] = Ys[i];
      ga.M[i] = Ms[i]; ga.Ncol[i] = Ns[i]; ga.blk0[i] = b0;
      b0 += nrow(Ms[i], 64);
    }
    gemm_multi<3><<<b0, 256, 0, stream>>>(ga);   // 908 blocks
  }

  // ---- phase E: layer-3 gather (head-mean/self-loop/relu) -> d_out ----
  gatE<<<NS, 256, 0, stream>>>(rpc + NG, meta, We3_gs, att3_gs,
                               xl3, xr3, bo3_gs, sl3, (float*)d_out);
}

// Round 13
// 300.425 us; speedup vs baseline: 1.2784x; 1.1363x over previous
//
#include <hip/hip_runtime.h>
#include <cstdint>
#include <cstddef>

// Problem constants (match reference)
#define NS 4000
#define NG 50000
#define NE 250000
#define DIM 128
#define NDST_TOT (NG + NS)          // 54000 combined CSR rows (sg then gs)

typedef __bf16 bf16_t;
typedef bf16_t bf16x8 __attribute__((ext_vector_type(8)));
typedef bf16_t bf16x4 __attribute__((ext_vector_type(4)));
typedef bf16_t bf16x2 __attribute__((ext_vector_type(2)));
typedef float floatx4 __attribute__((ext_vector_type(4)));

// ---------------------------------------------------------------------------
// Fused histogram + prep. Blocks [0, HIST_B): per-dst degree counts for both
// relations; the atomicAdd return value IS the edge's rank within its dst
// (stored as ushort) -> the later scatter needs NO atomics.
// Blocks [HIST_B, ...): 8 weight transposes (Wt[n][k]=bf16(W[k][n])) + bf16
// casts of x_mrna / x_gene (independent work, fused to save a launch).
// ---------------------------------------------------------------------------
#define HIST_B 977                  // ceil(NE/256)
#define WT_TOT 143360               // 4*16384 + 2*32768 + 4096 + 8192
struct HPArgs {
  const int* sgd; const int* gsd;
  int* cnt; unsigned short* rank_sg; unsigned short* rank_gs;
  const float* W[8]; bf16_t* Wt[8]; int N[8]; int e0[8];
  const float* xm; bf16_t* xbm;
  const float* xg; bf16_t* xbg;
};

__global__ __launch_bounds__(256) void histprep(HPArgs a) {
  if (blockIdx.x < HIST_B) {
    int e = blockIdx.x * 256 + threadIdx.x;
    if (e < NE) {
      a.rank_sg[e] = (unsigned short)atomicAdd(a.cnt + a.sgd[e], 1);
      a.rank_gs[e] = (unsigned short)atomicAdd(a.cnt + NG + a.gsd[e], 1);
    }
  } else {
    int u = (blockIdx.x - HIST_B) * 256 + threadIdx.x;
    if (u < WT_TOT) {
      int c = 0;
#pragma unroll
      for (int i = 1; i < 8; i++) if (u >= a.e0[i]) c = i;
      int idx = u - a.e0[c];
      int N = a.N[c];
      int k = idx / N, n = idx - k * N;
      a.Wt[c][n * 128 + k] = (bf16_t)a.W[c][idx];
    } else if (u < WT_TOT + 128000) {
      int j = (u - WT_TOT) * 4;
      float4 v = *reinterpret_cast<const float4*>(a.xm + j);
      bf16x4 b;
      b[0] = (bf16_t)v.x; b[1] = (bf16_t)v.y; b[2] = (bf16_t)v.z; b[3] = (bf16_t)v.w;
      *reinterpret_cast<bf16x4*>(a.xbm + j) = b;
    } else {
      int j = (u - WT_TOT - 128000) * 4;
      float4 v = *reinterpret_cast<const float4*>(a.xg + j);
      bf16x4 b;
      b[0] = (bf16_t)v.x; b[1] = (bf16_t)v.y; b[2] = (bf16_t)v.z; b[3] = (bf16_t)v.w;
      *reinterpret_cast<bf16x4*>(a.xbg + j) = b;
    }
  }
}

// ---------------------------------------------------------------------------
// 2-kernel parallel scan over n=54000 (53 blocks of 1024).
// NOTE: do NOT replace with a single-block serial-segment scan — measured
// 103 us (R8): per-thread serial global reads on one CU eat ~900-cyc
// cross-XCD misses. Parallel+coalesced is ~10 us total.
// ---------------------------------------------------------------------------
__global__ __launch_bounds__(1024) void scan1(const int* __restrict__ cnt,
                                              int* __restrict__ rp,
                                              int* __restrict__ csum, int n) {
  __shared__ int wsum[16];
  int i = blockIdx.x * 1024 + threadIdx.x;
  int lane = threadIdx.x & 63, w = threadIdx.x >> 6;
  int v = (i < n) ? cnt[i] : 0;
  int x = v;
#pragma unroll
  for (int off = 1; off < 64; off <<= 1) {
    int y = __shfl_up(x, off);
    if (lane >= off) x += y;
  }
  if (lane == 63) wsum[w] = x;
  __syncthreads();
  if (w == 0 && lane < 16) {
    int s = wsum[lane];
#pragma unroll
    for (int off = 1; off < 16; off <<= 1) {
      int y = __shfl_up(s, off);
      if (lane >= off) s += y;
    }
    wsum[lane] = s;
  }
  __syncthreads();
  int incl = x + (w ? wsum[w - 1] : 0);
  if (i < n) rp[i] = incl - v;
  if (threadIdx.x == 1023) csum[blockIdx.x] = incl;
}

__global__ __launch_bounds__(1024) void scan3(int* __restrict__ rp,
                                              const int* __restrict__ csum, int n) {
  __shared__ int pfx_s;
  if (threadIdx.x < 64) {
    int lane = threadIdx.x;
    int v = (lane < (int)blockIdx.x) ? csum[lane] : 0;   // blockIdx.x <= 52
#pragma unroll
    for (int off = 32; off > 0; off >>= 1) v += __shfl_down(v, off);
    if (lane == 0) pfx_s = v;
  }
  __syncthreads();
  int i = blockIdx.x * 1024 + threadIdx.x;
  if (i < n) rp[i] += pfx_s;
  if (i == 0) rp[n] = 2 * NE;                // static total sentinel
}

// ---------------------------------------------------------------------------
// Fused scatter + layer-1 GEMMs. Blocks [0, SCAT_B): atomic-free CSR scatter
// (rank precomputed in histprep) — memory-latency-bound, idle VALU/MFMA.
// Blocks [SCAT_B, ...): 5 MFMA GEMMs — MFMA-bound. Co-resident they overlap
// (MFMA and memory waves co-schedule ~max, not sum).
// ---------------------------------------------------------------------------
#define SCAT_B 1954                 // ceil(2*NE/256)
struct SGArgs {
  // scatter
  const int* sgd; const int* gsd; const int* sgs; const int* gss;
  const float* easg; const float* eags;
  const int* rp; const unsigned short* rank_sg; const unsigned short* rank_gs;
  uint2* meta;
  // gemm (5 configs)
  const bf16_t* X[5];
  const bf16_t* Wt[5];
  const float* Bv[5];
  bf16_t* Y[5];
  int M[5];
  int Ncol[5];
  int blk0[5];
};

__global__ __launch_bounds__(256) void scatgemm(SGArgs a) {
  if (blockIdx.x < SCAT_B) {
    int t = blockIdx.x * 256 + threadIdx.x;
    if (t < NE) {
      int d = a.sgd[t];
      uint2 pv; pv.x = (unsigned)a.sgs[t]; pv.y = __float_as_uint(a.easg[t]);
      a.meta[a.rp[d] + a.rank_sg[t]] = pv;
    } else if (t < 2 * NE) {
      int e = t - NE;
      int d = a.gsd[e];
      uint2 pv; pv.x = (unsigned)a.gss[e]; pv.y = __float_as_uint(a.eags[e]);
      a.meta[a.rp[NG + d] + a.rank_gs[e]] = pv;
    }
    return;
  }
  int bid = blockIdx.x - SCAT_B;
  int c = 0;
#pragma unroll
  for (int i = 1; i < 5; i++) if (bid >= a.blk0[i]) c = i;
  const bf16_t* X = a.X[c];
  const bf16_t* Wt = a.Wt[c];
  const float* B = a.Bv[c];
  bf16_t* Y = a.Y[c];
  int M = a.M[c];
  int N = a.Ncol[c];

  int wv = threadIdx.x >> 6, lane = threadIdx.x & 63;
  int m16 = lane & 15, quad = lane >> 4;
  int row0 = (bid - a.blk0[c]) * 64 + wv * 16;
  int arow = row0 + m16;
  const bf16_t* xp = X + (size_t)arow * DIM + quad * 8;

  bf16x8 afrag[4];
#pragma unroll
  for (int kk = 0; kk < 4; kk++) {
    bf16x8 av = {};
    if (arow < M) av = *reinterpret_cast<const bf16x8*>(xp + kk * 32);
    afrag[kk] = av;
  }

  int ncols = N >> 4;
  for (int nt = 0; nt < ncols; nt++) {
    int col = nt * 16 + m16;
    const bf16_t* bptr = Wt + (size_t)col * DIM + quad * 8;
    floatx4 acc = {0.f, 0.f, 0.f, 0.f};
#pragma unroll
    for (int kk = 0; kk < 4; kk++) {
      bf16x8 b = *reinterpret_cast<const bf16x8*>(bptr + kk * 32);
      acc = __builtin_amdgcn_mfma_f32_16x16x32_bf16(afrag[kk], b, acc, 0, 0, 0);
    }
    float bias = B[col];
    int orow = row0 + quad * 4;
#pragma unroll
    for (int r = 0; r < 4; r++)
      if (orow + r < M) Y[(size_t)(orow + r) * N + col] = (bf16_t)(acc[r] + bias);
  }
}

// ---------------------------------------------------------------------------
// Multi-config MFMA GEMM (phase D), runtime column count.
// ---------------------------------------------------------------------------
template <int NCFG>
struct GArgs {
  const bf16_t* X[NCFG];
  const bf16_t* Wt[NCFG];
  const float* Bv[NCFG];
  bf16_t* Y[NCFG];
  int M[NCFG];
  int Ncol[NCFG];
  int blk0[NCFG];
};

template <int NCFG>
__global__ __launch_bounds__(256) void gemm_multi(GArgs<NCFG> a) {
  int c = 0;
#pragma unroll
  for (int i = 1; i < NCFG; i++) if ((int)blockIdx.x >= a.blk0[i]) c = i;
  const bf16_t* X = a.X[c];
  const bf16_t* Wt = a.Wt[c];
  const float* B = a.Bv[c];
  bf16_t* Y = a.Y[c];
  int M = a.M[c];
  int N = a.Ncol[c];

  int wv = threadIdx.x >> 6, lane = threadIdx.x & 63;
  int m16 = lane & 15, quad = lane >> 4;
  int row0 = (blockIdx.x - a.blk0[c]) * 64 + wv * 16;
  int arow = row0 + m16;
  const bf16_t* xp = X + (size_t)arow * DIM + quad * 8;

  bf16x8 afrag[4];
#pragma unroll
  for (int kk = 0; kk < 4; kk++) {
    bf16x8 av = {};
    if (arow < M) av = *reinterpret_cast<const bf16x8*>(xp + kk * 32);
    afrag[kk] = av;
  }

  int ncols = N >> 4;
  for (int nt = 0; nt < ncols; nt++) {
    int col = nt * 16 + m16;
    const bf16_t* bptr = Wt + (size_t)col * DIM + quad * 8;
    floatx4 acc = {0.f, 0.f, 0.f, 0.f};
#pragma unroll
    for (int kk = 0; kk < 4; kk++) {
      bf16x8 b = *reinterpret_cast<const bf16x8*>(bptr + kk * 32);
      acc = __builtin_amdgcn_mfma_f32_16x16x32_bf16(afrag[kk], b, acc, 0, 0, 0);
    }
    float bias = B[col];
    int orow = row0 + quad * 4;
#pragma unroll
    for (int r = 0; r < 4; r++)
      if (orow + r < M) Y[(size_t)(orow + r) * N + col] = (bf16_t)(acc[r] + bias);
  }
}

// ---------------------------------------------------------------------------
// Fused phase-C gather, GROUP-PER-DST layout (NC=128, 8 ch per lane,
// 16-lane groups; head = gl>>2 -> logit reduce = 2 shfls, no dst select).
// Blocks [0, SGB): sg — 4 waves/block, each wave 4 dsts, one per group.
// Blocks [SGB, SGB+NS): gs — one block per dst; 16 groups walk LDS-staged
//   edges (block-coalesced meta stage), partials combined in LDS.
// NOTE: do NOT use readfirstlane+scalar branch per edge (R10: 73 us vs 55).
// ---------------------------------------------------------------------------
#define SGB 3125                    // 50000 dsts / (4 waves * 4 dsts)
__global__ __launch_bounds__(256) void gatC(
    const int* __restrict__ rp, const uint2* __restrict__ meta,
    const float* __restrict__ WeS, const float* __restrict__ attS,
    const float* __restrict__ boS,
    const bf16_t* __restrict__ xlS, const bf16_t* __restrict__ xrS,
    bf16_t* __restrict__ outS,
    const float* __restrict__ WeG, const float* __restrict__ attG,
    const float* __restrict__ boG,
    const bf16_t* __restrict__ xlG, const bf16_t* __restrict__ xrG,
    const bf16_t* __restrict__ slG, bf16_t* __restrict__ outG) {
  __shared__ uint2 smeta[256];
  __shared__ float lacc[16][128];
  __shared__ float lden[16][4];
  int lane = threadIdx.x & 63, wv = threadIdx.x >> 6;
  int gl = lane & 15, grp = lane >> 4;

  if (blockIdx.x < SGB) {
    // ---------------- sg: 4 dsts per wave, one per 16-lane group ----------
    int wid = blockIdx.x * 4 + wv;
    int d0 = wid * 4;
    int q = lane < 5 ? lane : 0;
    int rv = rp[d0 + q];
    int beg = __shfl(rv, grp), end = __shfl(rv, grp + 1);
    int dst = d0 + grp;

    float wev[8], atv[8], xrv[8], acc[8];
    *reinterpret_cast<float4*>(wev) = *reinterpret_cast<const float4*>(WeS + gl * 8);
    *reinterpret_cast<float4*>(wev + 4) = *reinterpret_cast<const float4*>(WeS + gl * 8 + 4);
    *reinterpret_cast<float4*>(atv) = *reinterpret_cast<const float4*>(attS + gl * 8);
    *reinterpret_cast<float4*>(atv + 4) = *reinterpret_cast<const float4*>(attS + gl * 8 + 4);
    bf16x8 xrb = *reinterpret_cast<const bf16x8*>(xrS + (size_t)dst * 128 + gl * 8);
#pragma unroll
    for (int v = 0; v < 8; v++) { xrv[v] = (float)xrb[v]; acc[v] = 0.f; }
    float den = 0.f;

    for (int i0 = beg; i0 < end; i0 += 16) {
      int cnt = min(16, end - i0);
      int s_l = 0; float ea_l = 0.f;
      if (gl < cnt) {
        uint2 mv = meta[i0 + gl];
        s_l = (int)mv.x; ea_l = __uint_as_float(mv.y);
      }
      // 1-deep prefetch of next edge's row
      int base = lane & 48;
      float ea = __shfl(ea_l, base);
      bf16x8 xlb = *reinterpret_cast<const bf16x8*>(
          xlS + (size_t)__shfl(s_l, base) * 128 + gl * 8);
      for (int k = 0; k < cnt; k++) {
        bf16x8 cur = xlb;
        float eac = ea;
        if (k + 1 < cnt) {
          ea = __shfl(ea_l, base + k + 1);
          xlb = *reinterpret_cast<const bf16x8*>(
              xlS + (size_t)__shfl(s_l, base + k + 1) * 128 + gl * 8);
        }
        float p = 0.f, xf[8];
#pragma unroll
        for (int v = 0; v < 8; v++) {
          xf[v] = (float)cur[v];
          float z = fmaf(eac, wev[v], xrv[v]) + xf[v];
          z = z > 0.f ? z : 0.2f * z;            // leaky_relu(., 0.2)
          p = fmaf(z, atv[v], p);
        }
        p += __shfl_xor(p, 1);
        p += __shfl_xor(p, 2);                   // head-wide logit (4 lanes)
        float ex = __expf(p);
        den += ex;
#pragma unroll
        for (int v = 0; v < 8; v++) acc[v] = fmaf(ex, xf[v], acc[v]);
      }
    }
    float inv = den > 0.f ? 1.f / den : 0.f;
    bf16x8 o;
#pragma unroll
    for (int v = 0; v < 8; v++) {
      float val = acc[v] * inv + boS[gl * 8 + v];
      o[v] = (bf16_t)(val > 0.f ? val : 0.f);
    }
    *reinterpret_cast<bf16x8*>(outS + (size_t)dst * 128 + gl * 8) = o;
  } else {
    // ---------------- gs: one block per dst, 16 groups over LDS stage -----
    int d = (int)blockIdx.x - SGB;
    const int* rpg = rp + NG;
    int G = wv * 4 + grp;
    int tid = threadIdx.x;

    float wev[8], atv[8], xrv[8], acc[8];
    *reinterpret_cast<float4*>(wev) = *reinterpret_cast<const float4*>(WeG + gl * 8);
    *reinterpret_cast<float4*>(wev + 4) = *reinterpret_cast<const float4*>(WeG + gl * 8 + 4);
    *reinterpret_cast<float4*>(atv) = *reinterpret_cast<const float4*>(attG + gl * 8);
    *reinterpret_cast<float4*>(atv + 4) = *reinterpret_cast<const float4*>(attG + gl * 8 + 4);
    bf16x8 xrb = *reinterpret_cast<const bf16x8*>(xrG + (size_t)d * 128 + gl * 8);
#pragma unroll
    for (int v = 0; v < 8; v++) { xrv[v] = (float)xrb[v]; acc[v] = 0.f; }
    float den = 0.f;

    int beg = rpg[d], end = rpg[d + 1];
    for (int base = beg; base < end; base += 256) {
      int cntb = min(256, end - base);
      __syncthreads();
      if (tid < cntb) smeta[tid] = meta[base + tid];
      __syncthreads();
      int e = G;
      uint2 mv; bf16x8 xlb;
      if (e < cntb) {
        mv = smeta[e];
        xlb = *reinterpret_cast<const bf16x8*>(xlG + (size_t)mv.x * 128 + gl * 8);
      }
      while (e < cntb) {
        bf16x8 cur = xlb;
        float eac = __uint_as_float(mv.y);
        int en = e + 16;
        if (en < cntb) {
          mv = smeta[en];
          xlb = *reinterpret_cast<const bf16x8*>(xlG + (size_t)mv.x * 128 + gl * 8);
        }
        float p = 0.f, xf[8];
#pragma unroll
        for (int v = 0; v < 8; v++) {
          xf[v] = (float)cur[v];
          float z = fmaf(eac, wev[v], xrv[v]) + xf[v];
          z = z > 0.f ? z : 0.2f * z;
          p = fmaf(z, atv[v], p);
        }
        p += __shfl_xor(p, 1);
        p += __shfl_xor(p, 2);
        float ex = __expf(p);
        den += ex;
#pragma unroll
        for (int v = 0; v < 8; v++) acc[v] = fmaf(ex, xf[v], acc[v]);
        e = en;
      }
    }
#pragma unroll
    for (int v = 0; v < 8; v++) lacc[G][gl * 8 + v] = acc[v];
    if ((gl & 3) == 0) lden[G][gl >> 2] = den;
    __syncthreads();
    if (wv != 0) return;
    int ch = lane * 2;
    int h = lane >> 4;
    float a0 = 0.f, a1 = 0.f, dh = 0.f;
#pragma unroll
    for (int g2 = 0; g2 < 16; g2++) {
      a0 += lacc[g2][ch];
      a1 += lacc[g2][ch + 1];
      dh += lden[g2][h];
    }
    float inv = dh > 0.f ? 1.f / dh : 0.f;
    float v0 = a0 * inv + boG[ch] + (float)slG[(size_t)d * 32 + (ch & 31)];
    float v1 = a1 * inv + boG[ch + 1] + (float)slG[(size_t)d * 32 + ((ch + 1) & 31)];
    bf16x2 o;
    o[0] = (bf16_t)(v0 > 0.f ? v0 : 0.f);
    o[1] = (bf16_t)(v1 > 0.f ? v1 : 0.f);
    *reinterpret_cast<bf16x2*>(outG + (size_t)d * 128 + ch) = o;
  }
}

// ---------------------------------------------------------------------------
// Phase-E gather: one block per dst; 16 groups of 16 lanes, 16 ch/lane
// (NC=256); LDS-staged edges + LDS combine; head-mean epilogue -> fp32 out.
// ---------------------------------------------------------------------------
__global__ __launch_bounds__(256) void gatE(
    const int* __restrict__ rp, const uint2* __restrict__ meta,
    const float* __restrict__ We, const float* __restrict__ att,
    const bf16_t* __restrict__ xl, const bf16_t* __restrict__ xr,
    const float* __restrict__ bo, const bf16_t* __restrict__ sl,
    float* __restrict__ out) {
  __shared__ uint2 smeta[256];
  __shared__ float lacc[16][256];
  __shared__ float lden[16][4];
  int lane = threadIdx.x & 63, wv = threadIdx.x >> 6;
  int gl = lane & 15, grp = lane >> 4;
  int G = wv * 4 + grp;
  int tid = threadIdx.x;
  int d = blockIdx.x;

  float wev[16], atv[16], xrv[16], acc[16];
#pragma unroll
  for (int b = 0; b < 4; b++) {
    *reinterpret_cast<float4*>(wev + b * 4) =
        *reinterpret_cast<const float4*>(We + gl * 16 + b * 4);
    *reinterpret_cast<float4*>(atv + b * 4) =
        *reinterpret_cast<const float4*>(att + gl * 16 + b * 4);
  }
  {
    bf16x8 r0 = *reinterpret_cast<const bf16x8*>(xr + (size_t)d * 256 + gl * 16);
    bf16x8 r1 = *reinterpret_cast<const bf16x8*>(xr + (size_t)d * 256 + gl * 16 + 8);
#pragma unroll
    for (int v = 0; v < 8; v++) { xrv[v] = (float)r0[v]; xrv[v + 8] = (float)r1[v]; }
  }
#pragma unroll
  for (int v = 0; v < 16; v++) acc[v] = 0.f;
  float den = 0.f;

  int beg = rp[d], end = rp[d + 1];
  for (int base = beg; base < end; base += 256) {
    int cntb = min(256, end - base);
    __syncthreads();
    if (tid < cntb) smeta[tid] = meta[base + tid];
    __syncthreads();
    int e = G;
    uint2 mv; bf16x8 x0, x1;
    if (e < cntb) {
      mv = smeta[e];
      x0 = *reinterpret_cast<const bf16x8*>(xl + (size_t)mv.x * 256 + gl * 16);
      x1 = *reinterpret_cast<const bf16x8*>(xl + (size_t)mv.x * 256 + gl * 16 + 8);
    }
    while (e < cntb) {
      bf16x8 c0 = x0, c1 = x1;
      float eac = __uint_as_float(mv.y);
      int en = e + 16;
      if (en < cntb) {
        mv = smeta[en];
        x0 = *reinterpret_cast<const bf16x8*>(xl + (size_t)mv.x * 256 + gl * 16);
        x1 = *reinterpret_cast<const bf16x8*>(xl + (size_t)mv.x * 256 + gl * 16 + 8);
      }
      float p = 0.f, xf[16];
#pragma unroll
      for (int v = 0; v < 8; v++) { xf[v] = (float)c0[v]; xf[v + 8] = (float)c1[v]; }
#pragma unroll
      for (int v = 0; v < 16; v++) {
        float z = fmaf(eac, wev[v], xrv[v]) + xf[v];
        z = z > 0.f ? z : 0.2f * z;              // leaky_relu(., 0.2)
        p = fmaf(z, atv[v], p);
      }
      p += __shfl_xor(p, 1);
      p += __shfl_xor(p, 2);                     // head-wide logit (4 lanes)
      float ex = __expf(p);
      den += ex;
#pragma unroll
      for (int v = 0; v < 16; v++) acc[v] = fmaf(ex, xf[v], acc[v]);
      e = en;
    }
  }
#pragma unroll
  for (int v = 0; v < 16; v++) lacc[G][gl * 16 + v] = acc[v];
  if ((gl & 3) == 0) lden[G][gl >> 2] = den;
  __syncthreads();
  if (wv != 0) return;
  int ch = lane * 4;
  int h = lane >> 4;
  float a[4] = {0.f, 0.f, 0.f, 0.f};
  float dh = 0.f;
#pragma unroll
  for (int g2 = 0; g2 < 16; g2++) {
#pragma unroll
    for (int v = 0; v < 4; v++) a[v] += lacc[g2][ch + v];
    dh += lden[g2][h];
  }
  float inv = dh > 0.f ? 1.f / dh : 0.f;
#pragma unroll
  for (int v = 0; v < 4; v++) {
    float s_ = a[v] * inv;
    s_ += __shfl_xor(s_, 16);
    s_ += __shfl_xor(s_, 32);                    // sum over the 4 heads
    if (lane < 16) {
      int c = (lane & 15) * 4 + v;
      float val = 0.25f * s_ + bo[c] + (float)sl[(size_t)d * 64 + c];
      out[(size_t)d * 64 + c] = val > 0.f ? val : 0.f;
    }
  }
}

// ---------------------------------------------------------------------------

static inline int nblk(long long threads) { return (int)((threads + 255) / 256); }
static inline int nrow(int M, int R) { return (M + R - 1) / R; }

extern "C" void kernel_launch(void* const* d_in, const int* in_sizes, int n_in,
                              void* d_out, int out_size, void* d_ws, size_t ws_size,
                              hipStream_t stream) {
  const float* x_mrna = (const float*)d_in[0];
  const float* x_gene = (const float*)d_in[1];
  const int* sg_src = (const int*)d_in[2];
  const int* sg_dst = (const int*)d_in[3];
  const int* gs_src = (const int*)d_in[4];
  const int* gs_dst = (const int*)d_in[5];
  const float* ea_sg = (const float*)d_in[6];
  const float* ea_gs = (const float*)d_in[7];
  const float* Wl1_sg = (const float*)d_in[8];
  const float* bl1_sg = (const float*)d_in[9];
  const float* Wr1_sg = (const float*)d_in[10];
  const float* br1_sg = (const float*)d_in[11];
  const float* We1_sg = (const float*)d_in[12];
  const float* att1_sg = (const float*)d_in[13];
  const float* bo1_sg = (const float*)d_in[14];
  const float* Wl1_gs = (const float*)d_in[15];
  const float* bl1_gs = (const float*)d_in[16];
  const float* Wr1_gs = (const float*)d_in[17];
  const float* br1_gs = (const float*)d_in[18];
  const float* We1_gs = (const float*)d_in[19];
  const float* att1_gs = (const float*)d_in[20];
  const float* bo1_gs = (const float*)d_in[21];
  const float* Wl3_gs = (const float*)d_in[22];
  const float* bl3_gs = (const float*)d_in[23];
  const float* Wr3_gs = (const float*)d_in[24];
  const float* br3_gs = (const float*)d_in[25];
  const float* We3_gs = (const float*)d_in[26];
  const float* att3_gs = (const float*)d_in[27];
  const float* bo3_gs = (const float*)d_in[28];
  const float* Wsl1 = (const float*)d_in[29];
  const float* bsl1 = (const float*)d_in[30];
  const float* Wsl3 = (const float*)d_in[31];
  const float* bsl3 = (const float*)d_in[32];

  // ---- workspace arena (fp32 element offsets), bf16 throughout ----
  float* ws = (float*)d_ws;
  bf16_t* xl1_gs = (bf16_t*)(ws + 0);        // bf16[50000*128] dead after C
  bf16_t* xl1_sg = (bf16_t*)(ws + 3200000);  // bf16[4000*128]  dead after C
  bf16_t* xr1_sg = (bf16_t*)(ws + 3456000);  // bf16[50000*128] dead after C
  bf16_t* xr1_gs = (bf16_t*)(ws + 6656000);  // bf16[4000*128]  dead after C
  bf16_t* xl3    = (bf16_t*)(ws + 0);        // bf16[50000*256] aliases [0,6.4M)
  bf16_t* xr3    = (bf16_t*)(ws + 6400000);  // bf16[4000*256]  aliases tail
  bf16_t* xb_mrna = (bf16_t*)(ws + 6912000); // bf16[4000*128]
  bf16_t* xb_gene = (bf16_t*)(ws + 7168000); // bf16[50000*128]
  bf16_t* x1_gene = (bf16_t*)(ws + 10368000);// bf16[50000*128]
  bf16_t* x1_mrna = (bf16_t*)(ws + 13568000);// bf16[4000*128]
  bf16_t* sl1    = (bf16_t*)(ws + 13824000); // bf16[4000*32]
  bf16_t* sl3    = (bf16_t*)(ws + 13856000); // bf16[4000*64]
  int*   ib      = (int*)(ws + 13920000);
  int* cnt  = ib + 0;                   // [54000] zeroed by memset
  int* rpc  = ib + 54000;               // [54001]
  int* csum = ib + 108002;              // [64]
  unsigned short* rank_sg = (unsigned short*)(ib + 108066);  // [250000]
  unsigned short* rank_gs = (unsigned short*)(ib + 233066);  // [250000]
  uint2* meta = (uint2*)(ib + 358066);  // [500000] packed (src, ea), 8B-aligned
  bf16_t* wtb = (bf16_t*)(ib + 1358066);// [143360] bf16 transposed weights
  // end: ib + 1429746 ints -> total ~61.4 MB

  bf16_t* wt_l1sg = wtb + 0;
  bf16_t* wt_r1sg = wtb + 16384;
  bf16_t* wt_l1gs = wtb + 32768;
  bf16_t* wt_r1gs = wtb + 49152;
  bf16_t* wt_l3   = wtb + 65536;   // [256*128]
  bf16_t* wt_r3   = wtb + 98304;   // [256*128]
  bf16_t* wt_sl1  = wtb + 131072;  // [32*128]
  bf16_t* wt_sl3  = wtb + 135168;  // [64*128]

  // zero histogram counters (ws is poisoned 0xAA before every timed call)
  hipMemsetAsync(cnt, 0, 54000 * sizeof(int), stream);

  // ---- phase A1: fused histogram(+rank) + weight/x prep ----
  {
    HPArgs hp;
    hp.sgd = sg_dst; hp.gsd = gs_dst;
    hp.cnt = cnt; hp.rank_sg = rank_sg; hp.rank_gs = rank_gs;
    const float* Wsrc[8] = {Wl1_sg, Wr1_sg, Wl1_gs, Wr1_gs, Wl3_gs, Wr3_gs, Wsl1, Wsl3};
    bf16_t* Wdst[8] = {wt_l1sg, wt_r1sg, wt_l1gs, wt_r1gs, wt_l3, wt_r3, wt_sl1, wt_sl3};
    int Nn[8] = {128, 128, 128, 128, 256, 256, 32, 64};
    int e0[8] = {0, 16384, 32768, 49152, 65536, 98304, 131072, 135168};
    for (int i = 0; i < 8; i++) { hp.W[i] = Wsrc[i]; hp.Wt[i] = Wdst[i]; hp.N[i] = Nn[i]; hp.e0[i] = e0[i]; }
    hp.xm = x_mrna; hp.xbm = xb_mrna;
    hp.xg = x_gene; hp.xbg = xb_gene;
    histprep<<<HIST_B + 7310, 256, 0, stream>>>(hp);   // 8287 blocks
  }

  // ---- phase A2: parallel 2-kernel scan ----
  int nchunks = (NDST_TOT + 1023) / 1024;            // 53
  scan1<<<nchunks, 1024, 0, stream>>>(cnt, rpc, csum, NDST_TOT);
  scan3<<<nchunks, 1024, 0, stream>>>(rpc, csum, NDST_TOT);

  // ---- phase B: fused atomic-free scatter + 5 layer-1 GEMMs ----
  {
    SGArgs sa;
    sa.sgd = sg_dst; sa.gsd = gs_dst; sa.sgs = sg_src; sa.gss = gs_src;
    sa.easg = ea_sg; sa.eags = ea_gs;
    sa.rp = rpc; sa.rank_sg = rank_sg; sa.rank_gs = rank_gs; sa.meta = meta;
    const bf16_t* Xs[5] = {xb_mrna, xb_gene, xb_gene, xb_mrna, xb_mrna};
    const bf16_t* Ws[5] = {wt_l1sg, wt_r1sg, wt_l1gs, wt_r1gs, wt_sl1};
    const float* Bs[5] = {bl1_sg, br1_sg, bl1_gs, br1_gs, bsl1};
    bf16_t* Ys[5] = {xl1_sg, xr1_sg, xl1_gs, xr1_gs, sl1};
    int Ms[5] = {NS, NG, NG, NS, NS};
    int Ns[5] = {128, 128, 128, 128, 32};
    int b0 = 0;
    for (int i = 0; i < 5; i++) {
      sa.X[i] = Xs[i]; sa.Wt[i] = Ws[i]; sa.Bv[i] = Bs[i]; sa.Y[i] = Ys[i];
      sa.M[i] = Ms[i]; sa.Ncol[i] = Ns[i]; sa.blk0[i] = b0;
      b0 += nrow(Ms[i], 64);
    }
    scatgemm<<<SCAT_B + b0, 256, 0, stream>>>(sa);   // 1954 + 1753 blocks
  }

  // ---- phase C: fused layer-1 gathers ----
  gatC<<<SGB + NS, 256, 0, stream>>>(
      rpc, meta,
      We1_sg, att1_sg, bo1_sg, xl1_sg, xr1_sg, x1_gene,
      We1_gs, att1_gs, bo1_gs, xl1_gs, xr1_gs, sl1, x1_mrna);

  // ---- phase D: 3 fused layer-3 GEMMs (incl. sl3) ----
  {
    GArgs<3> ga;
    const bf16_t* Xs[3] = {x1_gene, x1_mrna, x1_mrna};
    const bf16_t* Ws[3] = {wt_l3, wt_r3, wt_sl3};
    const float* Bs[3] = {bl3_gs, br3_gs, bsl3};
    bf16_t* Ys[3] = {xl3, xr3, sl3};
    int Ms[3] = {NG, NS, NS};
    int Ns[3] = {256, 256, 64};
    int b0 = 0;
    for (int i = 0; i < 3; i++) {
      ga.X[i] = Xs[i]; ga.Wt[i] = Ws[i]; ga.Bv[i] = Bs[i]; ga.Y[i] = Ys[i];
      ga.M[i] = Ms[i]; ga.Ncol[i] = Ns[i]; ga.blk0[i] = b0;
      b0 += nrow(Ms[i], 64);
    }
    gemm_multi<3><<<b0, 256, 0, stream>>>(ga);   // 908 blocks
  }

  // ---- phase E: layer-3 gather (head-mean/self-loop/relu) -> d_out ----
  gatE<<<NS, 256, 0, stream>>>(rpc + NG, meta, We3_gs, att3_gs,
                               xl3, xr3, bo3_gs, sl3, (float*)d_out);
}